// Round 16
// baseline (4636.328 us; speedup 1.0000x reference)
//
#include <hip/hip_runtime.h>
#include <hip/hip_bf16.h>

#define D_  768
#define B_  1024
#define N_  50000
#define K_  10
#define CH2_ 12500
#define NCH2_ 4
#define CM2_ 16
#define KPT_ 49   // ceil(12500/256)

__device__ __forceinline__ float gelu_f(float x){ return 0.5f*x*(1.0f+erff(x*0.70710678118654752f)); }
__device__ __forceinline__ double gelu_d(double x){ return 0.5*x*(1.0+erf(x*0.707106781186547524400844362105)); }

__device__ __forceinline__ float block_sum(float v, float* sm){
  #pragma unroll
  for (int o=32;o>0;o>>=1) v += __shfl_xor(v,o);
  __syncthreads();
  if ((threadIdx.x&63)==0) sm[threadIdx.x>>6]=v;
  __syncthreads();
  return (sm[0]+sm[1])+(sm[2]+sm[3]);
}
__device__ __forceinline__ double block_sum64(double v, double* sm){
  #pragma unroll
  for (int o=32;o>0;o>>=1) v += __shfl_xor(v,o);
  __syncthreads();
  if ((threadIdx.x&63)==0) sm[threadIdx.x>>6]=v;
  __syncthreads();
  return (sm[0]+sm[1])+(sm[2]+sm[3]);
}

// ============ f64 tiled GEMM (stage A/B): C = A @ W^T + bias ============
template<int ASRC, int EPI>
__global__ __launch_bounds__(256)
void dgemm_k(const void* __restrict__ Ap, const float* __restrict__ Wp, size_t woff,
             const float* __restrict__ biasp, size_t boff, double* __restrict__ Cp,
             int M, int N, int Kd, int ldc)
{
  __shared__ double As[16][64];
  __shared__ double Bs[16][64];
  const int t  = threadIdx.x;
  const int tx = t & 15, ty = t >> 4;
  const int row0 = blockIdx.y << 6, col0 = blockIdx.x << 6;
  const int lr = t >> 2, lk = (t & 3) << 2;
  const int ar = row0 + lr;
  const int wn = col0 + lr;
  const float* Wf = Wp + woff;
  double acc[4][4] = {};
  for (int k0 = 0; k0 < Kd; k0 += 16) {
    double av[4], wv[4];
    if (ar < M) {
      if (ASRC==0){
        const double* a = (const double*)Ap + (size_t)ar*Kd + k0 + lk;
        av[0]=a[0]; av[1]=a[1]; av[2]=a[2]; av[3]=a[3];
      } else {
        float4 v = *(const float4*)((const float*)Ap + (size_t)ar*Kd + k0 + lk);
        av[0]=(double)v.x; av[1]=(double)v.y; av[2]=(double)v.z; av[3]=(double)v.w;
      }
    } else { av[0]=av[1]=av[2]=av[3]=0.0; }
    if (wn < N) {
      float4 v = *(const float4*)(Wf + (size_t)wn*Kd + k0 + lk);
      wv[0]=(double)v.x; wv[1]=(double)v.y; wv[2]=(double)v.z; wv[3]=(double)v.w;
    } else { wv[0]=wv[1]=wv[2]=wv[3]=0.0; }
    #pragma unroll
    for (int u=0;u<4;++u){ As[lk+u][lr]=av[u]; Bs[lk+u][lr]=wv[u]; }
    __syncthreads();
    #pragma unroll
    for (int kk=0;kk<16;++kk){
      double aa[4], bb[4];
      #pragma unroll
      for (int u=0;u<4;++u){ aa[u]=As[kk][(ty<<2)+u]; bb[u]=Bs[kk][(tx<<2)+u]; }
      #pragma unroll
      for (int i=0;i<4;++i)
        #pragma unroll
        for (int j=0;j<4;++j)
          acc[i][j] = fma(aa[i], bb[j], acc[i][j]);
    }
    __syncthreads();
  }
  #pragma unroll
  for (int i=0;i<4;++i){
    int r=row0+(ty<<2)+i; if (r>=M) continue;
    #pragma unroll
    for (int j=0;j<4;++j){
      int n=col0+(tx<<2)+j; if (n>=N) continue;
      double v=acc[i][j];
      if (EPI) v += (double)(biasp+boff)[n];
      Cp[(size_t)r*ldc+n]=v;
    }
  }
}

// f64 LN + gelu (stage B)
__global__ __launch_bounds__(256)
void ln64_k(const double* __restrict__ x0, const float* __restrict__ g,
            const float* __restrict__ b, double* __restrict__ y)
{
  __shared__ double sm[4];
  size_t base = (size_t)blockIdx.x * D_;
  double xv[3]; double s=0.0;
  #pragma unroll
  for (int i=0;i<3;++i){ int c=threadIdx.x+(i<<8); xv[i]=x0[base+c]; s+=xv[i]; }
  s = block_sum64(s, sm);
  double m = s*(1.0/768.0);
  double vs=0.0;
  #pragma unroll
  for (int i=0;i<3;++i){ double d=xv[i]-m; vs+=d*d; }
  vs = block_sum64(vs, sm);
  double inv = 1.0/sqrt(vs*(1.0/768.0)+1e-5);
  #pragma unroll
  for (int i=0;i<3;++i){
    int c=threadIdx.x+(i<<8);
    double o=(xv[i]-m)*inv*(double)g[c]+(double)b[c];
    y[base+c]=gelu_d(o);
  }
}

// f64 inverse row norm, one WAVE per row.  SRC: 0 f64 ws, 1 f32 d_in.
template<int SRC>
__global__ __launch_bounds__(256)
void rnorm64w_k(const void* __restrict__ x, double* __restrict__ invn, int M)
{
  int gw = (blockIdx.x*256 + threadIdx.x) >> 6;
  int lane = threadIdx.x & 63;
  if (gw >= M) return;
  size_t base = (size_t)gw * D_;
  double s = 0.0;
  #pragma unroll
  for (int k=0;k<12;++k){
    double v = (SRC==1) ? (double)((const float*)x)[base+lane+(k<<6)]
                        : ((const double*)x)[base+lane+(k<<6)];
    s = fma(v,v,s);
  }
  #pragma unroll
  for (int o=32;o>0;o>>=1) s += __shfl_xor(s,o);
  if (lane==0) invn[gw] = 1.0/fmax(sqrt(s),1e-12);
}

__global__ void d2f_k(const double* __restrict__ src, float* __restrict__ dst, int n)
{ int i=blockIdx.x*256+threadIdx.x; if (i<n) dst[i]=(float)src[i]; }

__global__ void prep64_k(const float* __restrict__ vis, double* __restrict__ fusedin)
{
  int i = blockIdx.x*256+threadIdx.x;
  if (i >= B_*D_) return;
  int r=i/D_, c=i-r*D_;
  fusedin[(size_t)r*(2*D_)+c]=(double)vis[i];
}

// ============ f32 tiled GEMM ============
// ATY: 0 = A ws f32; 2 = A d_in f32; 3 = A d_in f32 with row gather.
// EPI: 0 none, 1 +bias, 2 +bias+gelu.  SCALE: epilogue ×inva32[r]×invw32[n].
template<int ATY, int EPI, int SCALE>
__global__ __launch_bounds__(256)
void gemm_k(const float* __restrict__ Ap, const int* __restrict__ ridx,
            const float* __restrict__ Wp, size_t woff,
            const float* __restrict__ biasp, size_t boff, float* __restrict__ Cp,
            const float* __restrict__ inva32, const float* __restrict__ invw32,
            int M, int N, int Kd, int ldc)
{
  __shared__ __align__(16) float As[16][64];
  __shared__ __align__(16) float Bs[16][64];
  const int t  = threadIdx.x;
  const int tx = t & 15, ty = t >> 4;
  const int row0 = blockIdx.y << 6, col0 = blockIdx.x << 6;
  const int lr = t >> 2, lk = (t & 3) << 2;
  const int ar = row0 + lr;
  const int wn = col0 + lr;
  const float* Wf = Wp + woff;
  float acc[4][4] = {};
  int arow = ar;
  if (ATY==3 && ar < M){
    arow = ridx[ar];
    if ((unsigned)arow >= (unsigned)N_) arow = 0;
  }
  for (int k0 = 0; k0 < Kd; k0 += 16) {
    float av[4], wv[4];
    if (ar < M) {
      float4 v = *(const float4*)(Ap + (size_t)arow*Kd + k0 + lk);
      av[0]=v.x; av[1]=v.y; av[2]=v.z; av[3]=v.w;
    } else { av[0]=av[1]=av[2]=av[3]=0.f; }
    if (wn < N) {
      float4 v = *(const float4*)(Wf + (size_t)wn*Kd + k0 + lk);
      wv[0]=v.x; wv[1]=v.y; wv[2]=v.z; wv[3]=v.w;
    } else { wv[0]=wv[1]=wv[2]=wv[3]=0.f; }
    #pragma unroll
    for (int u=0;u<4;++u){ As[lk+u][lr]=av[u]; Bs[lk+u][lr]=wv[u]; }
    __syncthreads();
    #pragma unroll
    for (int kk=0;kk<16;++kk){
      float4 a4 = *(const float4*)&As[kk][ty<<2];
      float4 b4 = *(const float4*)&Bs[kk][tx<<2];
      float aa[4]={a4.x,a4.y,a4.z,a4.w};
      float bb[4]={b4.x,b4.y,b4.z,b4.w};
      #pragma unroll
      for (int i=0;i<4;++i)
        #pragma unroll
        for (int j=0;j<4;++j)
          acc[i][j] = fmaf(aa[i], bb[j], acc[i][j]);
    }
    __syncthreads();
  }
  float bv[4];
  #pragma unroll
  for (int j=0;j<4;++j){
    int n=col0+(tx<<2)+j;
    bv[j] = (EPI>=1 && n<N) ? (biasp+boff)[n] : 0.f;
  }
  #pragma unroll
  for (int i=0;i<4;++i){
    int r=row0+(ty<<2)+i; if (r>=M) continue;
    float ia = (SCALE && r<M) ? inva32[r] : 1.f;
    #pragma unroll
    for (int j=0;j<4;++j){
      int n=col0+(tx<<2)+j; if (n>=N) continue;
      float v=acc[i][j]+bv[j];
      if (EPI==2) v=gelu_f(v);
      if (SCALE) v = v * ia * invw32[n];
      Cp[(size_t)r*ldc+n]=v;
    }
  }
}

// f32 LN
template<int RES>
__global__ __launch_bounds__(256)
void ln_k(const float* __restrict__ x0, const float* __restrict__ resf,
          const float* __restrict__ resb,
          const float* __restrict__ g, const float* __restrict__ b, size_t gboff,
          float* __restrict__ y)
{
  __shared__ float sm[4];
  size_t base = (size_t)blockIdx.x * D_;
  float xv[3]; float s=0.f;
  #pragma unroll
  for (int i=0;i<3;++i){
    int c=threadIdx.x+(i<<8);
    float tv=x0[base+c];
    if (RES==1) tv+=resf[base+c];
    if (RES==2) tv+=resb[base+c];
    xv[i]=tv; s+=tv;
  }
  s = block_sum(s, sm);
  float m = s*(1.0f/768.0f);
  float vs=0.f;
  #pragma unroll
  for (int i=0;i<3;++i){ float d=xv[i]-m; vs+=d*d; }
  vs = block_sum(vs, sm);
  float inv = rsqrtf(vs*(1.0f/768.0f)+1e-5f);
  #pragma unroll
  for (int i=0;i<3;++i){
    int c=threadIdx.x+(i<<8);
    y[base+c]=(xv[i]-m)*inv*(g+gboff)[c]+(b+gboff)[c];
  }
}

__global__ void add_k(const float* __restrict__ a, const float* __restrict__ b, float* __restrict__ c, int n)
{ int i=blockIdx.x*256+threadIdx.x; if (i<n) c[i]=a[i]+b[i]; }

// ===== stage C screen: per row-chunk, exact f32 top-16 via 16 parallel argmax rounds =====
__global__ __launch_bounds__(256)
void topk16_chunk_k(const float* __restrict__ simc, int* __restrict__ cand_id,
                    int off, int chunk, int cn, int ldc)
{
  __shared__ float rs[4];
  __shared__ int   ri[4];
  __shared__ float bs_s;
  __shared__ int   bi_s;
  int b = blockIdx.x, t = threadIdx.x;
  const float* rowp = simc + (size_t)b*ldc;
  float v[KPT_];
  #pragma unroll
  for (int k=0;k<KPT_;++k){
    int j = t + (k<<8);
    v[k] = (j < cn) ? rowp[j] : -1e30f;
  }
  float ps = 1e30f; int pi = -1;   // lexicographic threshold (prev extracted)
  for (int round=0; round<CM2_; ++round){
    float ms = -1e30f; int mi = 0x7fffffff;
    #pragma unroll
    for (int k=0;k<KPT_;++k){
      int j = t + (k<<8);
      float s = v[k];
      bool elig = (s < ps) || (s == ps && j > pi);
      if (elig && (s > ms || (s == ms && j < mi))){ ms = s; mi = j; }
    }
    #pragma unroll
    for (int o=32;o>0;o>>=1){
      float os = __shfl_xor(ms, o); int oi = __shfl_xor(mi, o);
      if (os > ms || (os == ms && oi < mi)){ ms = os; mi = oi; }
    }
    if ((t&63)==0){ rs[t>>6]=ms; ri[t>>6]=mi; }
    __syncthreads();
    if (t==0){
      float gs=rs[0]; int gi=ri[0];
      #pragma unroll
      for (int w=1;w<4;++w) if (rs[w]>gs || (rs[w]==gs && ri[w]<gi)){ gs=rs[w]; gi=ri[w]; }
      bs_s=gs; bi_s=gi;
      cand_id[((size_t)b*NCH2_+chunk)*CM2_+round] = (gi==0x7fffffff) ? 0x7fffffff : off+gi;
    }
    __syncthreads();
    ps = bs_s; pi = bi_s;
  }
}

// ===== f64 rescore, one WAVE per candidate (coalesced ans reads) =====
__global__ __launch_bounds__(256)
void rescore_k(const double* __restrict__ fproj64, const float* __restrict__ ans,
               const int* __restrict__ cand_id,
               const double* __restrict__ inv_fp64, const double* __restrict__ inv_an64,
               int* __restrict__ run_id)
{
  __shared__ double q[D_];
  __shared__ double sc_s[NCH2_*CM2_];
  __shared__ int    id_s[NCH2_*CM2_];
  int b = blockIdx.x, t = threadIdx.x;
  int wave = t>>6, lane = t&63;
  for (int i=t;i<D_;i+=256) q[i]=fproj64[(size_t)b*D_+i];
  __syncthreads();
  for (int c = wave; c < NCH2_*CM2_; c += 4){
    int j = cand_id[(size_t)b*NCH2_*CM2_ + c];
    bool ok = ((unsigned)j < (unsigned)N_);
    double acc = 0.0;
    if (ok){
      const float* ar = ans + (size_t)j*D_;
      #pragma unroll
      for (int k=0;k<12;++k){
        int d = lane + (k<<6);
        acc = fma(q[d], (double)ar[d], acc);
      }
    }
    #pragma unroll
    for (int o=32;o>0;o>>=1) acc += __shfl_xor(acc, o);
    if (lane==0){
      sc_s[c] = ok ? acc*inv_fp64[b]*inv_an64[j] : -1e300;
      id_s[c] = ok ? j : 0x7fffffff;
    }
  }
  __syncthreads();
  if (t==0){
    double gs[10]; int gi[10];
    #pragma unroll
    for (int k=0;k<10;++k){ gs[k]=-1e300; gi[k]=0x7fffffff; }
    for (int i=0;i<NCH2_*CM2_;++i){
      double s=sc_s[i]; int id=id_s[i];
      bool better9 = (s>gs[9]) || (s==gs[9] && id<gi[9]);
      if (!better9) continue;
      int q9=9;
      while (q9>0 && (gs[q9-1]<s || (gs[q9-1]==s && gi[q9-1]>id))){
        gs[q9]=gs[q9-1]; gi[q9]=gi[q9-1]; --q9;
      }
      gs[q9]=s; gi[q9]=id;
    }
    #pragma unroll
    for (int k=0;k<10;++k) run_id[b*10+k]=gi[k];
  }
}

// m4 attention: one thread per (b,h); K/V interleaved in kvh [B*10][1536].
__global__ __launch_bounds__(64)
void attn2_k(const float* __restrict__ qh, const float* __restrict__ kvh,
             float* __restrict__ o)
{
  int idx = blockIdx.x*64 + threadIdx.x;
  if (idx >= B_*8) return;
  int b = idx >> 3, h = idx & 7;
  const float* q = qh + (size_t)b*D_ + h*96;
  float p[10];
  float mx = -1e30f;
  for (int j=0;j<10;++j){
    const float* kr = kvh + ((size_t)(b*10+j))*1536 + h*96;
    float acc=0.f;
    for (int d=0;d<96;++d) acc = fmaf(q[d], kr[d], acc);
    p[j] = acc * 0.10206207261596575f;
    mx = fmaxf(mx, p[j]);
  }
  float sum=0.f;
  for (int j=0;j<10;++j){ p[j]=expf(p[j]-mx); sum+=p[j]; }
  float inv=1.0f/sum;
  for (int d=0;d<96;++d){
    float acc=0.f;
    for (int j=0;j<10;++j) acc = fmaf(p[j]*inv, kvh[((size_t)(b*10+j))*1536 + 768 + h*96 + d], acc);
    o[(size_t)b*D_ + h*96 + d] = acc;
  }
}

extern "C" void kernel_launch(void* const* d_in, const int* in_sizes, int n_in,
                              void* d_out, int out_size, void* d_ws, size_t ws_size,
                              hipStream_t stream)
{
  const float* vis      = (const float*)d_in[0];
  const float* txt      = (const float*)d_in[1];
  const float* ans      = (const float*)d_in[2];
  const float* vqa_in_w = (const float*)d_in[3];
  const float* vqa_in_b = (const float*)d_in[4];
  const float* vqa_out_w= (const float*)d_in[5];
  const float* vqa_out_b= (const float*)d_in[6];
  const float* fproj_w  = (const float*)d_in[7];
  const float* fproj_b  = (const float*)d_in[8];
  const float* fln_g    = (const float*)d_in[9];
  const float* fln_b    = (const float*)d_in[10];
  const float* sim_w    = (const float*)d_in[11];
  const float* sim_b    = (const float*)d_in[12];
  const float* m_in_w   = (const float*)d_in[13];
  const float* m_in_b   = (const float*)d_in[14];
  const float* m_out_w  = (const float*)d_in[15];
  const float* m_out_b  = (const float*)d_in[16];
  const float* ffn_w1   = (const float*)d_in[17];
  const float* ffn_b1   = (const float*)d_in[18];
  const float* ffn_w2   = (const float*)d_in[19];
  const float* ffn_b2   = (const float*)d_in[20];
  const float* ln_g     = (const float*)d_in[21];
  const float* ln_b     = (const float*)d_in[22];
  const float* outp_w   = (const float*)d_in[23];
  const float* outp_b   = (const float*)d_in[24];
  const float* open_w1  = (const float*)d_in[25];
  const float* open_b1  = (const float*)d_in[26];
  const float* open_w2  = (const float*)d_in[27];
  const float* open_b2  = (const float*)d_in[28];
  (void)n_in; (void)out_size;

  if (in_sizes[0]!=B_*D_) return;
  if (in_sizes[1]!=B_*D_) return;
  if (in_sizes[2]!=N_*D_) return;
  if (in_sizes[3]!=3*D_*D_) return;
  if (in_sizes[4]!=3*D_) return;
  if (in_sizes[5]!=D_*D_) return;
  if (in_sizes[7]!=D_*2*D_) return;
  if (in_sizes[9]!=D_) return;
  if (in_sizes[13]!=5*3*D_*D_) return;
  if (in_sizes[14]!=5*3*D_) return;
  if (in_sizes[15]!=5*D_*D_) return;
  if (in_sizes[17]!=4*D_*D_) return;
  if (in_sizes[19]!=4*D_*D_) return;
  if (in_sizes[21]!=4*D_) return;
  if (in_sizes[23]!=D_*D_) return;
  if (in_sizes[25]!=D_*D_) return;
  if (in_sizes[27]!=N_*D_) return;

  const size_t MBc = (size_t)1<<20;
  if (ws_size < 84*MBc) return;
  char* base = (char*)d_ws;
  // ---- phase 1 (f64 selection chain) ----
  double* fusedin64 = (double*)(base + 0);       // [0,12M)
  double* attn_v64  = (double*)(base + 12*MBc);  // [12,18M)
  double* ta64      = (double*)(base + 12*MBc);  // [12,18M) (attn_v64 dead)
  double* fused64   = (double*)(base + 18*MBc);  // [18,24M)
  double* fproj64   = (double*)(base + 60*MBc);  // [60,66M) persists -> rescore
  float*  fproj32   = (float*) (base + 66*MBc);  // [66,69M)
  float*  sim_ch    = (float*) (base + 0);       // [0,51.2M) screen (A/B temps dead)
  double* inv_an64  = (double*)(base + 69*MBc);  // 400KB
  double* inv_fp64  = (double*)(base + 70*MBc);  // 8KB
  float*  inv_an32  = (float*) (base + 71*MBc);  // 200KB
  float*  inv_fp32  = (float*) (base + 72*MBc);  // 4KB
  int*    cand_id   = (int*)   (base + 73*MBc);  // 256KB
  int*    run_id    = (int*)   (base + 78*MBc);  // 40KB (survives into phase 2)
  // ---- phase 2 (f32 residual stream; phase-1 regions dead) ----
  float* kvh  = (float*)(base + 0);              // [0,60M)   m4 K|V
  float* h1   = (float*)(base + 0);              // [0,12M)   FFN (kvh dead)
  float* ta   = (float*)(base + 60*MBc);         // [60,63M)
  float* tb   = (float*)(base + 63*MBc);         // [63,66M)
  float* tc   = (float*)(base + 66*MBc);         // [66,69M)
  float* fz0  = (float*)(base + 66*MBc);         // (tc dead)
  float* td   = (float*)(base + 69*MBc);         // [69,72M)
  float* fz   = (float*)(base + 69*MBc);         // (td dead)
  float* v1   = (float*)(base + 72*MBc);         // [72,75M) m0->m3
  float* o4   = (float*)(base + 72*MBc);         // m4 (v1 dead)
  float* outv = (float*)(base + 72*MBc);         // heads (o4 dead)
  float* t1   = (float*)(base + 75*MBc);         // [75,78M) m1->m2
  float* qh   = (float*)(base + 75*MBc);         // m4 (t1 dead)
  float* g1   = (float*)(base + 75*MBc);         // heads (qh dead)

  dim3 blk(256);
  auto gg = [](int M,int N){ return dim3((unsigned)((N+63)/64),(unsigned)((M+63)/64)); };
  auto ng = [](int M,int N){ return dim3((unsigned)(((size_t)M*N+255)/256)); };
  const size_t IW = (size_t)2304*768, OW = (size_t)768*768;
  const size_t VOFF = (size_t)1536*768, KOFF = (size_t)768*768;
  const int* NORIDX = nullptr;
  const float* NOS = nullptr;

  // ======== phase 1: selection (f64 chain, f32 screen, f64 rescore) ========
  prep64_k<<<ng(B_,D_), blk, 0, stream>>>(vis, fusedin64);
  dgemm_k<1,1><<<gg(B_,D_), blk, 0, stream>>>(vis, vqa_in_w, VOFF, vqa_in_b, 1536, attn_v64, B_, D_, D_, D_);
  dgemm_k<0,1><<<gg(B_,D_), blk, 0, stream>>>(attn_v64, vqa_out_w, 0, vqa_out_b, 0, fusedin64+D_, B_, D_, D_, 2*D_);
  dgemm_k<0,1><<<gg(B_,D_), blk, 0, stream>>>(fusedin64, fproj_w, 0, fproj_b, 0, ta64, B_, D_, 2*D_, D_);
  ln64_k<<<B_, blk, 0, stream>>>(ta64, fln_g, fln_b, fused64);
  dgemm_k<0,1><<<gg(B_,D_), blk, 0, stream>>>(fused64, sim_w, 0, sim_b, 0, fproj64, B_, D_, D_, D_);
  rnorm64w_k<1><<<(N_*64+255)/256, blk, 0, stream>>>(ans, inv_an64, N_);
  rnorm64w_k<0><<<(B_*64+255)/256, blk, 0, stream>>>(fproj64, inv_fp64, B_);
  d2f_k<<<(N_+255)/256, blk, 0, stream>>>(inv_an64, inv_an32, N_);
  d2f_k<<<(B_+255)/256, blk, 0, stream>>>(inv_fp64, inv_fp32, B_);
  d2f_k<<<(B_*D_+255)/256, blk, 0, stream>>>(fproj64, fproj32, B_*D_);
  for (int c=0;c<NCH2_;++c){
    gemm_k<0,0,1><<<gg(B_,CH2_), blk, 0, stream>>>(fproj32, NORIDX, ans, (size_t)c*CH2_*D_, nullptr, 0, sim_ch, inv_fp32, inv_an32 + c*CH2_, B_, CH2_, D_, CH2_);
    topk16_chunk_k<<<B_, blk, 0, stream>>>(sim_ch, cand_id, c*CH2_, c, CH2_, CH2_);
  }
  rescore_k<<<B_, blk, 0, stream>>>(fproj64, ans, cand_id, inv_fp64, inv_an64, run_id);

  // ======== phase 2: residual stream (f32) ========
  gemm_k<2,1,0><<<gg(B_,D_), blk, 0, stream>>>(vis, NORIDX, m_in_w, 0*IW+VOFF, m_in_b, 0*2304+1536, ta, NOS, NOS, B_, D_, D_, D_);
  gemm_k<0,1,0><<<gg(B_,D_), blk, 0, stream>>>(ta, NORIDX, m_out_w, 0*OW, m_out_b, 0*768, tb, NOS, NOS, B_, D_, D_, D_);
  ln_k<2><<<B_, blk, 0, stream>>>(tb, nullptr, vis, ln_g, ln_b, 0*D_, v1);
  gemm_k<2,1,0><<<gg(B_,D_), blk, 0, stream>>>(txt, NORIDX, m_in_w, 1*IW+VOFF, m_in_b, 1*2304+1536, ta, NOS, NOS, B_, D_, D_, D_);
  gemm_k<0,1,0><<<gg(B_,D_), blk, 0, stream>>>(ta, NORIDX, m_out_w, 1*OW, m_out_b, 1*768, tb, NOS, NOS, B_, D_, D_, D_);
  ln_k<2><<<B_, blk, 0, stream>>>(tb, nullptr, txt, ln_g, ln_b, 1*D_, t1);
  gemm_k<0,1,0><<<gg(B_,D_), blk, 0, stream>>>(t1, NORIDX, m_in_w, 2*IW+VOFF, m_in_b, 2*2304+1536, ta, NOS, NOS, B_, D_, D_, D_);
  gemm_k<0,1,0><<<gg(B_,D_), blk, 0, stream>>>(ta, NORIDX, m_out_w, 2*OW, m_out_b, 2*768, tb, NOS, NOS, B_, D_, D_, D_);
  gemm_k<0,1,0><<<gg(B_,D_), blk, 0, stream>>>(v1, NORIDX, m_in_w, 3*IW+VOFF, m_in_b, 3*2304+1536, tc, NOS, NOS, B_, D_, D_, D_);
  gemm_k<0,1,0><<<gg(B_,D_), blk, 0, stream>>>(tc, NORIDX, m_out_w, 3*OW, m_out_b, 3*768, td, NOS, NOS, B_, D_, D_, D_);
  ln_k<1><<<B_, blk, 0, stream>>>(tb, td, nullptr, ln_g, ln_b, 2*D_, fz0);
  // m4: q proj + fused K|V proj over gathered ans rows + attention
  gemm_k<0,1,0><<<gg(B_,D_), blk, 0, stream>>>(fz0, NORIDX, m_in_w, 4*IW, m_in_b, 4*2304, qh, NOS, NOS, B_, D_, D_, D_);
  gemm_k<3,1,0><<<gg(B_*K_,2*D_), blk, 0, stream>>>(ans, run_id, m_in_w, 4*IW+KOFF, m_in_b, 4*2304+768, kvh, NOS, NOS, B_*K_, 2*D_, D_, 2*D_);
  attn2_k<<<(B_*8+63)/64, dim3(64), 0, stream>>>(qh, kvh, o4);
  gemm_k<0,1,0><<<gg(B_,D_), blk, 0, stream>>>(o4, NORIDX, m_out_w, 4*OW, m_out_b, 4*768, ta, NOS, NOS, B_, D_, D_, D_);
  ln_k<1><<<B_, blk, 0, stream>>>(fz0, ta, nullptr, ln_g, ln_b, 3*D_, fz);
  // FFN + heads
  gemm_k<0,2,0><<<gg(B_,4*D_), blk, 0, stream>>>(fz, NORIDX, ffn_w1, 0, ffn_b1, 0, h1, NOS, NOS, B_, 4*D_, D_, 4*D_);
  gemm_k<0,1,0><<<gg(B_,D_), blk, 0, stream>>>(h1, NORIDX, ffn_w2, 0, ffn_b2, 0, tb, NOS, NOS, B_, D_, 4*D_, D_);
  add_k<<<ng(B_,D_), blk, 0, stream>>>(fz, tb, ta, B_*D_);
  gemm_k<0,1,0><<<gg(B_,D_), blk, 0, stream>>>(ta, NORIDX, outp_w, 0, outp_b, 0, outv, NOS, NOS, B_, D_, D_, D_);
  gemm_k<0,2,0><<<gg(B_,D_), blk, 0, stream>>>(outv, NORIDX, open_w1, 0, open_b1, 0, g1, NOS, NOS, B_, D_, D_, D_);
  gemm_k<0,1,0><<<gg(B_,N_), blk, 0, stream>>>(g1, NORIDX, open_w2, 0, open_b2, 0, (float*)d_out, NOS, NOS, B_, N_, D_, N_);
}

// Round 17
// 4462.581 us; speedup vs baseline: 1.0389x; 1.0389x over previous
//
#include <hip/hip_runtime.h>
#include <hip/hip_bf16.h>

#define D_  768
#define B_  1024
#define N_  50000
#define K_  10
#define CH2_ 12500
#define NCH2_ 4
#define CM2_ 16
#define KPT_ 49   // ceil(12500/256)

__device__ __forceinline__ float gelu_f(float x){ return 0.5f*x*(1.0f+erff(x*0.70710678118654752f)); }
__device__ __forceinline__ double gelu_d(double x){ return 0.5*x*(1.0+erf(x*0.707106781186547524400844362105)); }

__device__ __forceinline__ float block_sum(float v, float* sm){
  #pragma unroll
  for (int o=32;o>0;o>>=1) v += __shfl_xor(v,o);
  __syncthreads();
  if ((threadIdx.x&63)==0) sm[threadIdx.x>>6]=v;
  __syncthreads();
  return (sm[0]+sm[1])+(sm[2]+sm[3]);
}
__device__ __forceinline__ double block_sum64(double v, double* sm){
  #pragma unroll
  for (int o=32;o>0;o>>=1) v += __shfl_xor(v,o);
  __syncthreads();
  if ((threadIdx.x&63)==0) sm[threadIdx.x>>6]=v;
  __syncthreads();
  return (sm[0]+sm[1])+(sm[2]+sm[3]);
}

// ============ f64 tiled GEMM (stage A/B): C = A @ W^T + bias ============
template<int ASRC, int EPI>
__global__ __launch_bounds__(256)
void dgemm_k(const void* __restrict__ Ap, const float* __restrict__ Wp, size_t woff,
             const float* __restrict__ biasp, size_t boff, double* __restrict__ Cp,
             int M, int N, int Kd, int ldc)
{
  __shared__ double As[16][64];
  __shared__ double Bs[16][64];
  const int t  = threadIdx.x;
  const int tx = t & 15, ty = t >> 4;
  const int row0 = blockIdx.y << 6, col0 = blockIdx.x << 6;
  const int lr = t >> 2, lk = (t & 3) << 2;
  const int ar = row0 + lr;
  const int wn = col0 + lr;
  const float* Wf = Wp + woff;
  double acc[4][4] = {};
  for (int k0 = 0; k0 < Kd; k0 += 16) {
    double av[4], wv[4];
    if (ar < M) {
      if (ASRC==0){
        const double* a = (const double*)Ap + (size_t)ar*Kd + k0 + lk;
        av[0]=a[0]; av[1]=a[1]; av[2]=a[2]; av[3]=a[3];
      } else {
        float4 v = *(const float4*)((const float*)Ap + (size_t)ar*Kd + k0 + lk);
        av[0]=(double)v.x; av[1]=(double)v.y; av[2]=(double)v.z; av[3]=(double)v.w;
      }
    } else { av[0]=av[1]=av[2]=av[3]=0.0; }
    if (wn < N) {
      float4 v = *(const float4*)(Wf + (size_t)wn*Kd + k0 + lk);
      wv[0]=(double)v.x; wv[1]=(double)v.y; wv[2]=(double)v.z; wv[3]=(double)v.w;
    } else { wv[0]=wv[1]=wv[2]=wv[3]=0.0; }
    #pragma unroll
    for (int u=0;u<4;++u){ As[lk+u][lr]=av[u]; Bs[lk+u][lr]=wv[u]; }
    __syncthreads();
    #pragma unroll
    for (int kk=0;kk<16;++kk){
      double aa[4], bb[4];
      #pragma unroll
      for (int u=0;u<4;++u){ aa[u]=As[kk][(ty<<2)+u]; bb[u]=Bs[kk][(tx<<2)+u]; }
      #pragma unroll
      for (int i=0;i<4;++i)
        #pragma unroll
        for (int j=0;j<4;++j)
          acc[i][j] = fma(aa[i], bb[j], acc[i][j]);
    }
    __syncthreads();
  }
  #pragma unroll
  for (int i=0;i<4;++i){
    int r=row0+(ty<<2)+i; if (r>=M) continue;
    #pragma unroll
    for (int j=0;j<4;++j){
      int n=col0+(tx<<2)+j; if (n>=N) continue;
      double v=acc[i][j];
      if (EPI) v += (double)(biasp+boff)[n];
      Cp[(size_t)r*ldc+n]=v;
    }
  }
}

// f64 LN + gelu (stage B)
__global__ __launch_bounds__(256)
void ln64_k(const double* __restrict__ x0, const float* __restrict__ g,
            const float* __restrict__ b, double* __restrict__ y)
{
  __shared__ double sm[4];
  size_t base = (size_t)blockIdx.x * D_;
  double xv[3]; double s=0.0;
  #pragma unroll
  for (int i=0;i<3;++i){ int c=threadIdx.x+(i<<8); xv[i]=x0[base+c]; s+=xv[i]; }
  s = block_sum64(s, sm);
  double m = s*(1.0/768.0);
  double vs=0.0;
  #pragma unroll
  for (int i=0;i<3;++i){ double d=xv[i]-m; vs+=d*d; }
  vs = block_sum64(vs, sm);
  double inv = 1.0/sqrt(vs*(1.0/768.0)+1e-5);
  #pragma unroll
  for (int i=0;i<3;++i){
    int c=threadIdx.x+(i<<8);
    double o=(xv[i]-m)*inv*(double)g[c]+(double)b[c];
    y[base+c]=gelu_d(o);
  }
}

// f64 inverse row norm, one WAVE per row.  SRC: 0 f64 ws, 1 f32 d_in.
template<int SRC>
__global__ __launch_bounds__(256)
void rnorm64w_k(const void* __restrict__ x, double* __restrict__ invn, int M)
{
  int gw = (blockIdx.x*256 + threadIdx.x) >> 6;
  int lane = threadIdx.x & 63;
  if (gw >= M) return;
  size_t base = (size_t)gw * D_;
  double s = 0.0;
  #pragma unroll
  for (int k=0;k<12;++k){
    double v = (SRC==1) ? (double)((const float*)x)[base+lane+(k<<6)]
                        : ((const double*)x)[base+lane+(k<<6)];
    s = fma(v,v,s);
  }
  #pragma unroll
  for (int o=32;o>0;o>>=1) s += __shfl_xor(s,o);
  if (lane==0) invn[gw] = 1.0/fmax(sqrt(s),1e-12);
}

__global__ void d2f_k(const double* __restrict__ src, float* __restrict__ dst, int n)
{ int i=blockIdx.x*256+threadIdx.x; if (i<n) dst[i]=(float)src[i]; }

__global__ void prep64_k(const float* __restrict__ vis, double* __restrict__ fusedin)
{
  int i = blockIdx.x*256+threadIdx.x;
  if (i >= B_*D_) return;
  int r=i/D_, c=i-r*D_;
  fusedin[(size_t)r*(2*D_)+c]=(double)vis[i];
}

// ============ f32 128x128-tile GEMM (big shapes: logits + screen) ============
// C[M,N] = epi( A[M,Kd] @ W[N,Kd]^T + bias ) (×inva[r]×invw[n]).
// M must be a multiple of 128. Thread covers rows {ty*4+i, 64+ty*4+i},
// cols {tx*4+j, 64+tx*4+j} (split layout -> 2-way-max LDS conflicts, free).
template<int EPI, int SCALE>
__global__ __launch_bounds__(256)
void gemm128_k(const float* __restrict__ Ap, const float* __restrict__ Wp,
               const float* __restrict__ biasp, float* __restrict__ Cp,
               const float* __restrict__ inva, const float* __restrict__ invw,
               int M, int N, int Kd, int ldc)
{
  __shared__ __align__(16) float As[16][128];
  __shared__ __align__(16) float Bs[16][128];
  const int t = threadIdx.x;
  const int tx = t & 15, ty = t >> 4;
  const int row0 = blockIdx.y << 7, col0 = blockIdx.x << 7;
  const int lr = t >> 1, lk8 = (t & 1) << 3;
  const int arow = row0 + lr;                  // M multiple of 128 -> always valid
  const int wrow = col0 + lr;
  float acc[8][8] = {};
  for (int k0 = 0; k0 < Kd; k0 += 16){
    float4 a0 = *(const float4*)(Ap + (size_t)arow*Kd + k0 + lk8);
    float4 a1 = *(const float4*)(Ap + (size_t)arow*Kd + k0 + lk8 + 4);
    float4 b0 = {0,0,0,0}, b1 = {0,0,0,0};
    if (wrow < N){
      b0 = *(const float4*)(Wp + (size_t)wrow*Kd + k0 + lk8);
      b1 = *(const float4*)(Wp + (size_t)wrow*Kd + k0 + lk8 + 4);
    }
    As[lk8+0][lr]=a0.x; As[lk8+1][lr]=a0.y; As[lk8+2][lr]=a0.z; As[lk8+3][lr]=a0.w;
    As[lk8+4][lr]=a1.x; As[lk8+5][lr]=a1.y; As[lk8+6][lr]=a1.z; As[lk8+7][lr]=a1.w;
    Bs[lk8+0][lr]=b0.x; Bs[lk8+1][lr]=b0.y; Bs[lk8+2][lr]=b0.z; Bs[lk8+3][lr]=b0.w;
    Bs[lk8+4][lr]=b1.x; Bs[lk8+5][lr]=b1.y; Bs[lk8+6][lr]=b1.z; Bs[lk8+7][lr]=b1.w;
    __syncthreads();
    #pragma unroll
    for (int kk=0; kk<16; ++kk){
      float4 aL = *(const float4*)&As[kk][ty<<2];
      float4 aH = *(const float4*)&As[kk][64 + (ty<<2)];
      float4 bL = *(const float4*)&Bs[kk][tx<<2];
      float4 bH = *(const float4*)&Bs[kk][64 + (tx<<2)];
      float av[8] = {aL.x,aL.y,aL.z,aL.w, aH.x,aH.y,aH.z,aH.w};
      float bv[8] = {bL.x,bL.y,bL.z,bL.w, bH.x,bH.y,bH.z,bH.w};
      #pragma unroll
      for (int i=0;i<8;++i)
        #pragma unroll
        for (int j=0;j<8;++j)
          acc[i][j] = fmaf(av[i], bv[j], acc[i][j]);
    }
    __syncthreads();
  }
  #pragma unroll
  for (int i=0;i<8;++i){
    int r = row0 + ((i<4) ? ((ty<<2)+i) : (64 + (ty<<2) + i - 4));
    float ia = SCALE ? inva[r] : 1.f;
    #pragma unroll
    for (int jh=0;jh<2;++jh){
      int cbase = col0 + ((jh==0) ? (tx<<2) : (64 + (tx<<2)));
      #pragma unroll
      for (int j=0;j<4;++j){
        int c = cbase + j;
        if (c >= N) continue;
        float v = acc[i][jh*4+j];
        if (EPI) v += biasp[c];
        if (SCALE) v = v * ia * invw[c];
        Cp[(size_t)r*ldc + c] = v;
      }
    }
  }
}

// ============ f32 tiled GEMM (small shapes) ============
// ATY: 0 = A ws f32; 2 = A d_in f32; 3 = A d_in f32 with row gather.
// EPI: 0 none, 1 +bias, 2 +bias+gelu.  SCALE: epilogue ×inva32[r]×invw32[n].
template<int ATY, int EPI, int SCALE>
__global__ __launch_bounds__(256)
void gemm_k(const float* __restrict__ Ap, const int* __restrict__ ridx,
            const float* __restrict__ Wp, size_t woff,
            const float* __restrict__ biasp, size_t boff, float* __restrict__ Cp,
            const float* __restrict__ inva32, const float* __restrict__ invw32,
            int M, int N, int Kd, int ldc)
{
  __shared__ __align__(16) float As[16][64];
  __shared__ __align__(16) float Bs[16][64];
  const int t  = threadIdx.x;
  const int tx = t & 15, ty = t >> 4;
  const int row0 = blockIdx.y << 6, col0 = blockIdx.x << 6;
  const int lr = t >> 2, lk = (t & 3) << 2;
  const int ar = row0 + lr;
  const int wn = col0 + lr;
  const float* Wf = Wp + woff;
  float acc[4][4] = {};
  int arow = ar;
  if (ATY==3 && ar < M){
    arow = ridx[ar];
    if ((unsigned)arow >= (unsigned)N_) arow = 0;
  }
  for (int k0 = 0; k0 < Kd; k0 += 16) {
    float av[4], wv[4];
    if (ar < M) {
      float4 v = *(const float4*)(Ap + (size_t)arow*Kd + k0 + lk);
      av[0]=v.x; av[1]=v.y; av[2]=v.z; av[3]=v.w;
    } else { av[0]=av[1]=av[2]=av[3]=0.f; }
    if (wn < N) {
      float4 v = *(const float4*)(Wf + (size_t)wn*Kd + k0 + lk);
      wv[0]=v.x; wv[1]=v.y; wv[2]=v.z; wv[3]=v.w;
    } else { wv[0]=wv[1]=wv[2]=wv[3]=0.f; }
    #pragma unroll
    for (int u=0;u<4;++u){ As[lk+u][lr]=av[u]; Bs[lk+u][lr]=wv[u]; }
    __syncthreads();
    #pragma unroll
    for (int kk=0;kk<16;++kk){
      float4 a4 = *(const float4*)&As[kk][ty<<2];
      float4 b4 = *(const float4*)&Bs[kk][tx<<2];
      float aa[4]={a4.x,a4.y,a4.z,a4.w};
      float bb[4]={b4.x,b4.y,b4.z,b4.w};
      #pragma unroll
      for (int i=0;i<4;++i)
        #pragma unroll
        for (int j=0;j<4;++j)
          acc[i][j] = fmaf(aa[i], bb[j], acc[i][j]);
    }
    __syncthreads();
  }
  float bv[4];
  #pragma unroll
  for (int j=0;j<4;++j){
    int n=col0+(tx<<2)+j;
    bv[j] = (EPI>=1 && n<N) ? (biasp+boff)[n] : 0.f;
  }
  #pragma unroll
  for (int i=0;i<4;++i){
    int r=row0+(ty<<2)+i; if (r>=M) continue;
    float ia = (SCALE && r<M) ? inva32[r] : 1.f;
    #pragma unroll
    for (int j=0;j<4;++j){
      int n=col0+(tx<<2)+j; if (n>=N) continue;
      float v=acc[i][j]+bv[j];
      if (EPI==2) v=gelu_f(v);
      if (SCALE) v = v * ia * invw32[n];
      Cp[(size_t)r*ldc+n]=v;
    }
  }
}

// f32 LN
template<int RES>
__global__ __launch_bounds__(256)
void ln_k(const float* __restrict__ x0, const float* __restrict__ resf,
          const float* __restrict__ resb,
          const float* __restrict__ g, const float* __restrict__ b, size_t gboff,
          float* __restrict__ y)
{
  __shared__ float sm[4];
  size_t base = (size_t)blockIdx.x * D_;
  float xv[3]; float s=0.f;
  #pragma unroll
  for (int i=0;i<3;++i){
    int c=threadIdx.x+(i<<8);
    float tv=x0[base+c];
    if (RES==1) tv+=resf[base+c];
    if (RES==2) tv+=resb[base+c];
    xv[i]=tv; s+=tv;
  }
  s = block_sum(s, sm);
  float m = s*(1.0f/768.0f);
  float vs=0.f;
  #pragma unroll
  for (int i=0;i<3;++i){ float d=xv[i]-m; vs+=d*d; }
  vs = block_sum(vs, sm);
  float inv = rsqrtf(vs*(1.0f/768.0f)+1e-5f);
  #pragma unroll
  for (int i=0;i<3;++i){
    int c=threadIdx.x+(i<<8);
    y[base+c]=(xv[i]-m)*inv*(g+gboff)[c]+(b+gboff)[c];
  }
}

__global__ void add_k(const float* __restrict__ a, const float* __restrict__ b, float* __restrict__ c, int n)
{ int i=blockIdx.x*256+threadIdx.x; if (i<n) c[i]=a[i]+b[i]; }

// ===== stage C screen: per row-chunk, exact f32 top-16 via 16 parallel argmax rounds =====
__global__ __launch_bounds__(256)
void topk16_chunk_k(const float* __restrict__ simc, int* __restrict__ cand_id,
                    int off, int chunk, int cn, int ldc)
{
  __shared__ float rs[4];
  __shared__ int   ri[4];
  __shared__ float bs_s;
  __shared__ int   bi_s;
  int b = blockIdx.x, t = threadIdx.x;
  const float* rowp = simc + (size_t)b*ldc;
  float v[KPT_];
  #pragma unroll
  for (int k=0;k<KPT_;++k){
    int j = t + (k<<8);
    v[k] = (j < cn) ? rowp[j] : -1e30f;
  }
  float ps = 1e30f; int pi = -1;   // lexicographic threshold (prev extracted)
  for (int round=0; round<CM2_; ++round){
    float ms = -1e30f; int mi = 0x7fffffff;
    #pragma unroll
    for (int k=0;k<KPT_;++k){
      int j = t + (k<<8);
      float s = v[k];
      bool elig = (s < ps) || (s == ps && j > pi);
      if (elig && (s > ms || (s == ms && j < mi))){ ms = s; mi = j; }
    }
    #pragma unroll
    for (int o=32;o>0;o>>=1){
      float os = __shfl_xor(ms, o); int oi = __shfl_xor(mi, o);
      if (os > ms || (os == ms && oi < mi)){ ms = os; mi = oi; }
    }
    if ((t&63)==0){ rs[t>>6]=ms; ri[t>>6]=mi; }
    __syncthreads();
    if (t==0){
      float gs=rs[0]; int gi=ri[0];
      #pragma unroll
      for (int w=1;w<4;++w) if (rs[w]>gs || (rs[w]==gs && ri[w]<gi)){ gs=rs[w]; gi=ri[w]; }
      bs_s=gs; bi_s=gi;
      cand_id[((size_t)b*NCH2_+chunk)*CM2_+round] = (gi==0x7fffffff) ? 0x7fffffff : off+gi;
    }
    __syncthreads();
    ps = bs_s; pi = bi_s;
  }
}

// ===== f64 rescore, one WAVE per candidate (coalesced ans reads) =====
__global__ __launch_bounds__(256)
void rescore_k(const double* __restrict__ fproj64, const float* __restrict__ ans,
               const int* __restrict__ cand_id,
               const double* __restrict__ inv_fp64, const double* __restrict__ inv_an64,
               int* __restrict__ run_id)
{
  __shared__ double q[D_];
  __shared__ double sc_s[NCH2_*CM2_];
  __shared__ int    id_s[NCH2_*CM2_];
  int b = blockIdx.x, t = threadIdx.x;
  int wave = t>>6, lane = t&63;
  for (int i=t;i<D_;i+=256) q[i]=fproj64[(size_t)b*D_+i];
  __syncthreads();
  for (int c = wave; c < NCH2_*CM2_; c += 4){
    int j = cand_id[(size_t)b*NCH2_*CM2_ + c];
    bool ok = ((unsigned)j < (unsigned)N_);
    double acc = 0.0;
    if (ok){
      const float* ar = ans + (size_t)j*D_;
      #pragma unroll
      for (int k=0;k<12;++k){
        int d = lane + (k<<6);
        acc = fma(q[d], (double)ar[d], acc);
      }
    }
    #pragma unroll
    for (int o=32;o>0;o>>=1) acc += __shfl_xor(acc, o);
    if (lane==0){
      sc_s[c] = ok ? acc*inv_fp64[b]*inv_an64[j] : -1e300;
      id_s[c] = ok ? j : 0x7fffffff;
    }
  }
  __syncthreads();
  if (t==0){
    double gs[10]; int gi[10];
    #pragma unroll
    for (int k=0;k<10;++k){ gs[k]=-1e300; gi[k]=0x7fffffff; }
    for (int i=0;i<NCH2_*CM2_;++i){
      double s=sc_s[i]; int id=id_s[i];
      bool better9 = (s>gs[9]) || (s==gs[9] && id<gi[9]);
      if (!better9) continue;
      int q9=9;
      while (q9>0 && (gs[q9-1]<s || (gs[q9-1]==s && gi[q9-1]>id))){
        gs[q9]=gs[q9-1]; gi[q9]=gi[q9-1]; --q9;
      }
      gs[q9]=s; gi[q9]=id;
    }
    #pragma unroll
    for (int k=0;k<10;++k) run_id[b*10+k]=gi[k];
  }
}

// m4 attention: one thread per (b,h); K/V interleaved in kvh [B*10][1536].
__global__ __launch_bounds__(64)
void attn2_k(const float* __restrict__ qh, const float* __restrict__ kvh,
             float* __restrict__ o)
{
  int idx = blockIdx.x*64 + threadIdx.x;
  if (idx >= B_*8) return;
  int b = idx >> 3, h = idx & 7;
  const float* q = qh + (size_t)b*D_ + h*96;
  float p[10];
  float mx = -1e30f;
  for (int j=0;j<10;++j){
    const float* kr = kvh + ((size_t)(b*10+j))*1536 + h*96;
    float acc=0.f;
    for (int d=0;d<96;++d) acc = fmaf(q[d], kr[d], acc);
    p[j] = acc * 0.10206207261596575f;
    mx = fmaxf(mx, p[j]);
  }
  float sum=0.f;
  for (int j=0;j<10;++j){ p[j]=expf(p[j]-mx); sum+=p[j]; }
  float inv=1.0f/sum;
  for (int d=0;d<96;++d){
    float acc=0.f;
    for (int j=0;j<10;++j) acc = fmaf(p[j]*inv, kvh[((size_t)(b*10+j))*1536 + 768 + h*96 + d], acc);
    o[(size_t)b*D_ + h*96 + d] = acc;
  }
}

extern "C" void kernel_launch(void* const* d_in, const int* in_sizes, int n_in,
                              void* d_out, int out_size, void* d_ws, size_t ws_size,
                              hipStream_t stream)
{
  const float* vis      = (const float*)d_in[0];
  const float* txt      = (const float*)d_in[1];
  const float* ans      = (const float*)d_in[2];
  const float* vqa_in_w = (const float*)d_in[3];
  const float* vqa_in_b = (const float*)d_in[4];
  const float* vqa_out_w= (const float*)d_in[5];
  const float* vqa_out_b= (const float*)d_in[6];
  const float* fproj_w  = (const float*)d_in[7];
  const float* fproj_b  = (const float*)d_in[8];
  const float* fln_g    = (const float*)d_in[9];
  const float* fln_b    = (const float*)d_in[10];
  const float* sim_w    = (const float*)d_in[11];
  const float* sim_b    = (const float*)d_in[12];
  const float* m_in_w   = (const float*)d_in[13];
  const float* m_in_b   = (const float*)d_in[14];
  const float* m_out_w  = (const float*)d_in[15];
  const float* m_out_b  = (const float*)d_in[16];
  const float* ffn_w1   = (const float*)d_in[17];
  const float* ffn_b1   = (const float*)d_in[18];
  const float* ffn_w2   = (const float*)d_in[19];
  const float* ffn_b2   = (const float*)d_in[20];
  const float* ln_g     = (const float*)d_in[21];
  const float* ln_b     = (const float*)d_in[22];
  const float* outp_w   = (const float*)d_in[23];
  const float* outp_b   = (const float*)d_in[24];
  const float* open_w1  = (const float*)d_in[25];
  const float* open_b1  = (const float*)d_in[26];
  const float* open_w2  = (const float*)d_in[27];
  const float* open_b2  = (const float*)d_in[28];
  (void)n_in; (void)out_size;

  if (in_sizes[0]!=B_*D_) return;
  if (in_sizes[1]!=B_*D_) return;
  if (in_sizes[2]!=N_*D_) return;
  if (in_sizes[3]!=3*D_*D_) return;
  if (in_sizes[4]!=3*D_) return;
  if (in_sizes[5]!=D_*D_) return;
  if (in_sizes[7]!=D_*2*D_) return;
  if (in_sizes[9]!=D_) return;
  if (in_sizes[13]!=5*3*D_*D_) return;
  if (in_sizes[14]!=5*3*D_) return;
  if (in_sizes[15]!=5*D_*D_) return;
  if (in_sizes[17]!=4*D_*D_) return;
  if (in_sizes[19]!=4*D_*D_) return;
  if (in_sizes[21]!=4*D_) return;
  if (in_sizes[23]!=D_*D_) return;
  if (in_sizes[25]!=D_*D_) return;
  if (in_sizes[27]!=N_*D_) return;

  const size_t MBc = (size_t)1<<20;
  if (ws_size < 84*MBc) return;
  char* base = (char*)d_ws;
  // ---- phase 1 (f64 selection chain) ----
  double* fusedin64 = (double*)(base + 0);       // [0,12M)
  double* attn_v64  = (double*)(base + 12*MBc);  // [12,18M)
  double* ta64      = (double*)(base + 12*MBc);  // [12,18M) (attn_v64 dead)
  double* fused64   = (double*)(base + 18*MBc);  // [18,24M)
  double* fproj64   = (double*)(base + 60*MBc);  // [60,66M) persists -> rescore
  float*  fproj32   = (float*) (base + 66*MBc);  // [66,69M)
  float*  sim_ch    = (float*) (base + 0);       // [0,51.2M) screen (A/B temps dead)
  double* inv_an64  = (double*)(base + 69*MBc);  // 400KB
  double* inv_fp64  = (double*)(base + 70*MBc);  // 8KB
  float*  inv_an32  = (float*) (base + 71*MBc);  // 200KB
  float*  inv_fp32  = (float*) (base + 72*MBc);  // 4KB
  int*    cand_id   = (int*)   (base + 73*MBc);  // 256KB
  int*    run_id    = (int*)   (base + 78*MBc);  // 40KB (survives into phase 2)
  // ---- phase 2 (f32 residual stream; phase-1 regions dead) ----
  float* kvh  = (float*)(base + 0);              // [0,60M)   m4 K|V
  float* h1   = (float*)(base + 0);              // [0,12M)   FFN (kvh dead)
  float* ta   = (float*)(base + 60*MBc);         // [60,63M)
  float* tb   = (float*)(base + 63*MBc);         // [63,66M)
  float* tc   = (float*)(base + 66*MBc);         // [66,69M)
  float* fz0  = (float*)(base + 66*MBc);         // (tc dead)
  float* td   = (float*)(base + 69*MBc);         // [69,72M)
  float* fz   = (float*)(base + 69*MBc);         // (td dead)
  float* v1   = (float*)(base + 72*MBc);         // [72,75M) m0->m3
  float* o4   = (float*)(base + 72*MBc);         // m4 (v1 dead)
  float* outv = (float*)(base + 72*MBc);         // heads (o4 dead)
  float* t1   = (float*)(base + 75*MBc);         // [75,78M) m1->m2
  float* qh   = (float*)(base + 75*MBc);         // m4 (t1 dead)
  float* g1   = (float*)(base + 75*MBc);         // heads (qh dead)

  dim3 blk(256);
  auto gg = [](int M,int N){ return dim3((unsigned)((N+63)/64),(unsigned)((M+63)/64)); };
  auto g128 = [](int M,int N){ return dim3((unsigned)((N+127)/128),(unsigned)(M/128)); };
  auto ng = [](int M,int N){ return dim3((unsigned)(((size_t)M*N+255)/256)); };
  const size_t IW = (size_t)2304*768, OW = (size_t)768*768;
  const size_t VOFF = (size_t)1536*768, KOFF = (size_t)768*768;
  const int* NORIDX = nullptr;
  const float* NOS = nullptr;

  // ======== phase 1: selection (f64 chain, f32 screen, f64 rescore) ========
  prep64_k<<<ng(B_,D_), blk, 0, stream>>>(vis, fusedin64);
  dgemm_k<1,1><<<gg(B_,D_), blk, 0, stream>>>(vis, vqa_in_w, VOFF, vqa_in_b, 1536, attn_v64, B_, D_, D_, D_);
  dgemm_k<0,1><<<gg(B_,D_), blk, 0, stream>>>(attn_v64, vqa_out_w, 0, vqa_out_b, 0, fusedin64+D_, B_, D_, D_, 2*D_);
  dgemm_k<0,1><<<gg(B_,D_), blk, 0, stream>>>(fusedin64, fproj_w, 0, fproj_b, 0, ta64, B_, D_, 2*D_, D_);
  ln64_k<<<B_, blk, 0, stream>>>(ta64, fln_g, fln_b, fused64);
  dgemm_k<0,1><<<gg(B_,D_), blk, 0, stream>>>(fused64, sim_w, 0, sim_b, 0, fproj64, B_, D_, D_, D_);
  rnorm64w_k<1><<<(N_*64+255)/256, blk, 0, stream>>>(ans, inv_an64, N_);
  rnorm64w_k<0><<<(B_*64+255)/256, blk, 0, stream>>>(fproj64, inv_fp64, B_);
  d2f_k<<<(N_+255)/256, blk, 0, stream>>>(inv_an64, inv_an32, N_);
  d2f_k<<<(B_+255)/256, blk, 0, stream>>>(inv_fp64, inv_fp32, B_);
  d2f_k<<<(B_*D_+255)/256, blk, 0, stream>>>(fproj64, fproj32, B_*D_);
  for (int c=0;c<NCH2_;++c){
    gemm128_k<0,1><<<g128(B_,CH2_), blk, 0, stream>>>(fproj32, ans + (size_t)c*CH2_*D_, nullptr, sim_ch, inv_fp32, inv_an32 + c*CH2_, B_, CH2_, D_, CH2_);
    topk16_chunk_k<<<B_, blk, 0, stream>>>(sim_ch, cand_id, c*CH2_, c, CH2_, CH2_);
  }
  rescore_k<<<B_, blk, 0, stream>>>(fproj64, ans, cand_id, inv_fp64, inv_an64, run_id);

  // ======== phase 2: residual stream (f32) ========
  gemm_k<2,1,0><<<gg(B_,D_), blk, 0, stream>>>(vis, NORIDX, m_in_w, 0*IW+VOFF, m_in_b, 0*2304+1536, ta, NOS, NOS, B_, D_, D_, D_);
  gemm_k<0,1,0><<<gg(B_,D_), blk, 0, stream>>>(ta, NORIDX, m_out_w, 0*OW, m_out_b, 0*768, tb, NOS, NOS, B_, D_, D_, D_);
  ln_k<2><<<B_, blk, 0, stream>>>(tb, nullptr, vis, ln_g, ln_b, 0*D_, v1);
  gemm_k<2,1,0><<<gg(B_,D_), blk, 0, stream>>>(txt, NORIDX, m_in_w, 1*IW+VOFF, m_in_b, 1*2304+1536, ta, NOS, NOS, B_, D_, D_, D_);
  gemm_k<0,1,0><<<gg(B_,D_), blk, 0, stream>>>(ta, NORIDX, m_out_w, 1*OW, m_out_b, 1*768, tb, NOS, NOS, B_, D_, D_, D_);
  ln_k<2><<<B_, blk, 0, stream>>>(tb, nullptr, txt, ln_g, ln_b, 1*D_, t1);
  gemm_k<0,1,0><<<gg(B_,D_), blk, 0, stream>>>(t1, NORIDX, m_in_w, 2*IW+VOFF, m_in_b, 2*2304+1536, ta, NOS, NOS, B_, D_, D_, D_);
  gemm_k<0,1,0><<<gg(B_,D_), blk, 0, stream>>>(ta, NORIDX, m_out_w, 2*OW, m_out_b, 2*768, tb, NOS, NOS, B_, D_, D_, D_);
  gemm_k<0,1,0><<<gg(B_,D_), blk, 0, stream>>>(v1, NORIDX, m_in_w, 3*IW+VOFF, m_in_b, 3*2304+1536, tc, NOS, NOS, B_, D_, D_, D_);
  gemm_k<0,1,0><<<gg(B_,D_), blk, 0, stream>>>(tc, NORIDX, m_out_w, 3*OW, m_out_b, 3*768, td, NOS, NOS, B_, D_, D_, D_);
  ln_k<1><<<B_, blk, 0, stream>>>(tb, td, nullptr, ln_g, ln_b, 2*D_, fz0);
  // m4: q proj + fused K|V proj over gathered ans rows + attention
  gemm_k<0,1,0><<<gg(B_,D_), blk, 0, stream>>>(fz0, NORIDX, m_in_w, 4*IW, m_in_b, 4*2304, qh, NOS, NOS, B_, D_, D_, D_);
  gemm_k<3,1,0><<<gg(B_*K_,2*D_), blk, 0, stream>>>(ans, run_id, m_in_w, 4*IW+KOFF, m_in_b, 4*2304+768, kvh, NOS, NOS, B_*K_, 2*D_, D_, 2*D_);
  attn2_k<<<(B_*8+63)/64, dim3(64), 0, stream>>>(qh, kvh, o4);
  gemm_k<0,1,0><<<gg(B_,D_), blk, 0, stream>>>(o4, NORIDX, m_out_w, 4*OW, m_out_b, 4*768, ta, NOS, NOS, B_, D_, D_, D_);
  ln_k<1><<<B_, blk, 0, stream>>>(fz0, ta, nullptr, ln_g, ln_b, 3*D_, fz);
  // FFN + heads
  gemm_k<0,2,0><<<gg(B_,4*D_), blk, 0, stream>>>(fz, NORIDX, ffn_w1, 0, ffn_b1, 0, h1, NOS, NOS, B_, 4*D_, D_, 4*D_);
  gemm_k<0,1,0><<<gg(B_,D_), blk, 0, stream>>>(h1, NORIDX, ffn_w2, 0, ffn_b2, 0, tb, NOS, NOS, B_, D_, 4*D_, D_);
  add_k<<<ng(B_,D_), blk, 0, stream>>>(fz, tb, ta, B_*D_);
  gemm_k<0,1,0><<<gg(B_,D_), blk, 0, stream>>>(ta, NORIDX, outp_w, 0, outp_b, 0, outv, NOS, NOS, B_, D_, D_, D_);
  gemm_k<0,2,0><<<gg(B_,D_), blk, 0, stream>>>(outv, NORIDX, open_w1, 0, open_b1, 0, g1, NOS, NOS, B_, D_, D_, D_);
  gemm128_k<1,0><<<g128(B_,N_), blk, 0, stream>>>(g1, open_w2, open_b2, (float*)d_out, NOS, NOS, B_, N_, D_, N_);
}

// Round 18
// 4196.410 us; speedup vs baseline: 1.1048x; 1.0634x over previous
//
#include <hip/hip_runtime.h>
#include <hip/hip_bf16.h>

#define D_  768
#define B_  1024
#define N_  50000
#define K_  10
#define CH2_ 12500
#define NCH2_ 4
#define CM2_ 16
#define KPT_ 49   // ceil(12500/256)

__device__ __forceinline__ float gelu_f(float x){ return 0.5f*x*(1.0f+erff(x*0.70710678118654752f)); }
__device__ __forceinline__ double gelu_d(double x){ return 0.5*x*(1.0+erf(x*0.707106781186547524400844362105)); }

__device__ __forceinline__ float block_sum(float v, float* sm){
  #pragma unroll
  for (int o=32;o>0;o>>=1) v += __shfl_xor(v,o);
  __syncthreads();
  if ((threadIdx.x&63)==0) sm[threadIdx.x>>6]=v;
  __syncthreads();
  return (sm[0]+sm[1])+(sm[2]+sm[3]);
}
__device__ __forceinline__ double block_sum64(double v, double* sm){
  #pragma unroll
  for (int o=32;o>0;o>>=1) v += __shfl_xor(v,o);
  __syncthreads();
  if ((threadIdx.x&63)==0) sm[threadIdx.x>>6]=v;
  __syncthreads();
  return (sm[0]+sm[1])+(sm[2]+sm[3]);
}

// ============ f64 tiled GEMM (stage A/B): C = A @ W^T + bias ============
template<int ASRC, int EPI>
__global__ __launch_bounds__(256)
void dgemm_k(const void* __restrict__ Ap, const float* __restrict__ Wp, size_t woff,
             const float* __restrict__ biasp, size_t boff, double* __restrict__ Cp,
             int M, int N, int Kd, int ldc)
{
  __shared__ double As[16][64];
  __shared__ double Bs[16][64];
  const int t  = threadIdx.x;
  const int tx = t & 15, ty = t >> 4;
  const int row0 = blockIdx.y << 6, col0 = blockIdx.x << 6;
  const int lr = t >> 2, lk = (t & 3) << 2;
  const int ar = row0 + lr;
  const int wn = col0 + lr;
  const float* Wf = Wp + woff;
  double acc[4][4] = {};
  for (int k0 = 0; k0 < Kd; k0 += 16) {
    double av[4], wv[4];
    if (ar < M) {
      if (ASRC==0){
        const double* a = (const double*)Ap + (size_t)ar*Kd + k0 + lk;
        av[0]=a[0]; av[1]=a[1]; av[2]=a[2]; av[3]=a[3];
      } else {
        float4 v = *(const float4*)((const float*)Ap + (size_t)ar*Kd + k0 + lk);
        av[0]=(double)v.x; av[1]=(double)v.y; av[2]=(double)v.z; av[3]=(double)v.w;
      }
    } else { av[0]=av[1]=av[2]=av[3]=0.0; }
    if (wn < N) {
      float4 v = *(const float4*)(Wf + (size_t)wn*Kd + k0 + lk);
      wv[0]=(double)v.x; wv[1]=(double)v.y; wv[2]=(double)v.z; wv[3]=(double)v.w;
    } else { wv[0]=wv[1]=wv[2]=wv[3]=0.0; }
    #pragma unroll
    for (int u=0;u<4;++u){ As[lk+u][lr]=av[u]; Bs[lk+u][lr]=wv[u]; }
    __syncthreads();
    #pragma unroll
    for (int kk=0;kk<16;++kk){
      double aa[4], bb[4];
      #pragma unroll
      for (int u=0;u<4;++u){ aa[u]=As[kk][(ty<<2)+u]; bb[u]=Bs[kk][(tx<<2)+u]; }
      #pragma unroll
      for (int i=0;i<4;++i)
        #pragma unroll
        for (int j=0;j<4;++j)
          acc[i][j] = fma(aa[i], bb[j], acc[i][j]);
    }
    __syncthreads();
  }
  #pragma unroll
  for (int i=0;i<4;++i){
    int r=row0+(ty<<2)+i; if (r>=M) continue;
    #pragma unroll
    for (int j=0;j<4;++j){
      int n=col0+(tx<<2)+j; if (n>=N) continue;
      double v=acc[i][j];
      if (EPI) v += (double)(biasp+boff)[n];
      Cp[(size_t)r*ldc+n]=v;
    }
  }
}

// f64 LN + gelu (stage B)
__global__ __launch_bounds__(256)
void ln64_k(const double* __restrict__ x0, const float* __restrict__ g,
            const float* __restrict__ b, double* __restrict__ y)
{
  __shared__ double sm[4];
  size_t base = (size_t)blockIdx.x * D_;
  double xv[3]; double s=0.0;
  #pragma unroll
  for (int i=0;i<3;++i){ int c=threadIdx.x+(i<<8); xv[i]=x0[base+c]; s+=xv[i]; }
  s = block_sum64(s, sm);
  double m = s*(1.0/768.0);
  double vs=0.0;
  #pragma unroll
  for (int i=0;i<3;++i){ double d=xv[i]-m; vs+=d*d; }
  vs = block_sum64(vs, sm);
  double inv = 1.0/sqrt(vs*(1.0/768.0)+1e-5);
  #pragma unroll
  for (int i=0;i<3;++i){
    int c=threadIdx.x+(i<<8);
    double o=(xv[i]-m)*inv*(double)g[c]+(double)b[c];
    y[base+c]=gelu_d(o);
  }
}

// f64 inverse row norm, one WAVE per row.  SRC: 0 f64 ws, 1 f32 d_in.
template<int SRC>
__global__ __launch_bounds__(256)
void rnorm64w_k(const void* __restrict__ x, double* __restrict__ invn, int M)
{
  int gw = (blockIdx.x*256 + threadIdx.x) >> 6;
  int lane = threadIdx.x & 63;
  if (gw >= M) return;
  size_t base = (size_t)gw * D_;
  double s = 0.0;
  #pragma unroll
  for (int k=0;k<12;++k){
    double v = (SRC==1) ? (double)((const float*)x)[base+lane+(k<<6)]
                        : ((const double*)x)[base+lane+(k<<6)];
    s = fma(v,v,s);
  }
  #pragma unroll
  for (int o=32;o>0;o>>=1) s += __shfl_xor(s,o);
  if (lane==0) invn[gw] = 1.0/fmax(sqrt(s),1e-12);
}

__global__ void d2f_k(const double* __restrict__ src, float* __restrict__ dst, int n)
{ int i=blockIdx.x*256+threadIdx.x; if (i<n) dst[i]=(float)src[i]; }

__global__ void prep64_k(const float* __restrict__ vis, double* __restrict__ fusedin)
{
  int i = blockIdx.x*256+threadIdx.x;
  if (i >= B_*D_) return;
  int r=i/D_, c=i-r*D_;
  fusedin[(size_t)r*(2*D_)+c]=(double)vis[i];
}

// ============ f32 128x128-tile GEMM, software-pipelined ============
// C[M,N] = epi( A[M,Kd] @ W[N,Kd]^T + bias ) (×inva[r]×invw[n]).
// M multiple of 128.  GATHER: logical A-row r reads ans-row ridx[r].
template<int EPI, int SCALE, int GATHER>
__global__ __launch_bounds__(256)
void gemm128_k(const float* __restrict__ Ap, const int* __restrict__ ridx,
               const float* __restrict__ Wp,
               const float* __restrict__ biasp, float* __restrict__ Cp,
               const float* __restrict__ inva, const float* __restrict__ invw,
               int M, int N, int Kd, int ldc)
{
  __shared__ __align__(16) float As[16][128];
  __shared__ __align__(16) float Bs[16][128];
  const int t = threadIdx.x;
  const int tx = t & 15, ty = t >> 4;
  const int row0 = blockIdx.y << 7, col0 = blockIdx.x << 7;
  const int lr = t >> 1, lk8 = (t & 1) << 3;
  int arow = row0 + lr;                       // M multiple of 128 -> valid
  if (GATHER){ int gidx = ridx[arow]; arow = ((unsigned)gidx < (unsigned)N_) ? gidx : 0; }
  const int wrow = col0 + lr;
  const bool wok = (wrow < N);
  const float* aptr = Ap + (size_t)arow*Kd + lk8;
  const float* wptr = Wp + (size_t)(wok ? wrow : 0)*Kd + lk8;
  float acc[8][8] = {};
  float4 z; z.x=z.y=z.z=z.w=0.f;
  float4 a0 = *(const float4*)(aptr);
  float4 a1 = *(const float4*)(aptr+4);
  float4 b0 = wok ? *(const float4*)(wptr)   : z;
  float4 b1 = wok ? *(const float4*)(wptr+4) : z;
  const int nt = Kd >> 4;
  for (int it=0; it<nt; ++it){
    As[lk8+0][lr]=a0.x; As[lk8+1][lr]=a0.y; As[lk8+2][lr]=a0.z; As[lk8+3][lr]=a0.w;
    As[lk8+4][lr]=a1.x; As[lk8+5][lr]=a1.y; As[lk8+6][lr]=a1.z; As[lk8+7][lr]=a1.w;
    Bs[lk8+0][lr]=b0.x; Bs[lk8+1][lr]=b0.y; Bs[lk8+2][lr]=b0.z; Bs[lk8+3][lr]=b0.w;
    Bs[lk8+4][lr]=b1.x; Bs[lk8+5][lr]=b1.y; Bs[lk8+6][lr]=b1.z; Bs[lk8+7][lr]=b1.w;
    __syncthreads();
    if (it+1 < nt){                              // prefetch next tile into regs
      const float* ap = aptr + ((it+1)<<4);
      a0 = *(const float4*)(ap); a1 = *(const float4*)(ap+4);
      if (wok){
        const float* wp = wptr + ((it+1)<<4);
        b0 = *(const float4*)(wp); b1 = *(const float4*)(wp+4);
      }
    }
    #pragma unroll
    for (int kk=0; kk<16; ++kk){
      float4 aL = *(const float4*)&As[kk][ty<<2];
      float4 aH = *(const float4*)&As[kk][64 + (ty<<2)];
      float4 bL = *(const float4*)&Bs[kk][tx<<2];
      float4 bH = *(const float4*)&Bs[kk][64 + (tx<<2)];
      float av[8] = {aL.x,aL.y,aL.z,aL.w, aH.x,aH.y,aH.z,aH.w};
      float bv[8] = {bL.x,bL.y,bL.z,bL.w, bH.x,bH.y,bH.z,bH.w};
      #pragma unroll
      for (int i=0;i<8;++i)
        #pragma unroll
        for (int j=0;j<8;++j)
          acc[i][j] = fmaf(av[i], bv[j], acc[i][j]);
    }
    __syncthreads();
  }
  #pragma unroll
  for (int i=0;i<8;++i){
    int r = row0 + ((i<4) ? ((ty<<2)+i) : (64 + (ty<<2) + i - 4));
    float ia = SCALE ? inva[r] : 1.f;
    #pragma unroll
    for (int jh=0;jh<2;++jh){
      int cbase = col0 + ((jh==0) ? (tx<<2) : (64 + (tx<<2)));
      #pragma unroll
      for (int j=0;j<4;++j){
        int c = cbase + j;
        if (c >= N) continue;
        float v = acc[i][jh*4+j];
        if (EPI) v += biasp[c];
        if (SCALE) v = v * ia * invw[c];
        Cp[(size_t)r*ldc + c] = v;
      }
    }
  }
}

// ============ f32 tiled GEMM (small shapes) ============
template<int ATY, int EPI, int SCALE>
__global__ __launch_bounds__(256)
void gemm_k(const float* __restrict__ Ap, const int* __restrict__ ridx,
            const float* __restrict__ Wp, size_t woff,
            const float* __restrict__ biasp, size_t boff, float* __restrict__ Cp,
            const float* __restrict__ inva32, const float* __restrict__ invw32,
            int M, int N, int Kd, int ldc)
{
  __shared__ __align__(16) float As[16][64];
  __shared__ __align__(16) float Bs[16][64];
  const int t  = threadIdx.x;
  const int tx = t & 15, ty = t >> 4;
  const int row0 = blockIdx.y << 6, col0 = blockIdx.x << 6;
  const int lr = t >> 2, lk = (t & 3) << 2;
  const int ar = row0 + lr;
  const int wn = col0 + lr;
  const float* Wf = Wp + woff;
  float acc[4][4] = {};
  int arow = ar;
  if (ATY==3 && ar < M){
    arow = ridx[ar];
    if ((unsigned)arow >= (unsigned)N_) arow = 0;
  }
  for (int k0 = 0; k0 < Kd; k0 += 16) {
    float av[4], wv[4];
    if (ar < M) {
      float4 v = *(const float4*)(Ap + (size_t)arow*Kd + k0 + lk);
      av[0]=v.x; av[1]=v.y; av[2]=v.z; av[3]=v.w;
    } else { av[0]=av[1]=av[2]=av[3]=0.f; }
    if (wn < N) {
      float4 v = *(const float4*)(Wf + (size_t)wn*Kd + k0 + lk);
      wv[0]=v.x; wv[1]=v.y; wv[2]=v.z; wv[3]=v.w;
    } else { wv[0]=wv[1]=wv[2]=wv[3]=0.f; }
    #pragma unroll
    for (int u=0;u<4;++u){ As[lk+u][lr]=av[u]; Bs[lk+u][lr]=wv[u]; }
    __syncthreads();
    #pragma unroll
    for (int kk=0;kk<16;++kk){
      float4 a4 = *(const float4*)&As[kk][ty<<2];
      float4 b4 = *(const float4*)&Bs[kk][tx<<2];
      float aa[4]={a4.x,a4.y,a4.z,a4.w};
      float bb[4]={b4.x,b4.y,b4.z,b4.w};
      #pragma unroll
      for (int i=0;i<4;++i)
        #pragma unroll
        for (int j=0;j<4;++j)
          acc[i][j] = fmaf(aa[i], bb[j], acc[i][j]);
    }
    __syncthreads();
  }
  float bv[4];
  #pragma unroll
  for (int j=0;j<4;++j){
    int n=col0+(tx<<2)+j;
    bv[j] = (EPI>=1 && n<N) ? (biasp+boff)[n] : 0.f;
  }
  #pragma unroll
  for (int i=0;i<4;++i){
    int r=row0+(ty<<2)+i; if (r>=M) continue;
    float ia = (SCALE && r<M) ? inva32[r] : 1.f;
    #pragma unroll
    for (int j=0;j<4;++j){
      int n=col0+(tx<<2)+j; if (n>=N) continue;
      float v=acc[i][j]+bv[j];
      if (EPI==2) v=gelu_f(v);
      if (SCALE) v = v * ia * invw32[n];
      Cp[(size_t)r*ldc+n]=v;
    }
  }
}

// ============ z-batched pair GEMM: two independent 1024x768x768 (+bias) ============
__global__ __launch_bounds__(256)
void gemm2_k(const float* __restrict__ A0, const float* __restrict__ A1,
             const float* __restrict__ W, size_t w0, size_t w1,
             const float* __restrict__ bias, size_t bo0, size_t bo1,
             float* __restrict__ C0, float* __restrict__ C1)
{
  const float* Ap = blockIdx.z ? A1 : A0;
  const float* Wf = W + (blockIdx.z ? w1 : w0);
  const float* bp = bias + (blockIdx.z ? bo1 : bo0);
  float* Cp = blockIdx.z ? C1 : C0;
  __shared__ __align__(16) float As[16][64];
  __shared__ __align__(16) float Bs[16][64];
  const int t  = threadIdx.x;
  const int tx = t & 15, ty = t >> 4;
  const int row0 = blockIdx.y << 6, col0 = blockIdx.x << 6;
  const int lr = t >> 2, lk = (t & 3) << 2;
  float acc[4][4] = {};
  for (int k0 = 0; k0 < D_; k0 += 16) {
    float4 va = *(const float4*)(Ap + (size_t)(row0+lr)*D_ + k0 + lk);
    float4 vw = *(const float4*)(Wf + (size_t)(col0+lr)*D_ + k0 + lk);
    As[lk+0][lr]=va.x; As[lk+1][lr]=va.y; As[lk+2][lr]=va.z; As[lk+3][lr]=va.w;
    Bs[lk+0][lr]=vw.x; Bs[lk+1][lr]=vw.y; Bs[lk+2][lr]=vw.z; Bs[lk+3][lr]=vw.w;
    __syncthreads();
    #pragma unroll
    for (int kk=0;kk<16;++kk){
      float4 a4 = *(const float4*)&As[kk][ty<<2];
      float4 b4 = *(const float4*)&Bs[kk][tx<<2];
      float aa[4]={a4.x,a4.y,a4.z,a4.w};
      float bb[4]={b4.x,b4.y,b4.z,b4.w};
      #pragma unroll
      for (int i=0;i<4;++i)
        #pragma unroll
        for (int j=0;j<4;++j)
          acc[i][j] = fmaf(aa[i], bb[j], acc[i][j]);
    }
    __syncthreads();
  }
  #pragma unroll
  for (int i=0;i<4;++i){
    int r=row0+(ty<<2)+i;
    #pragma unroll
    for (int j=0;j<4;++j){
      int n=col0+(tx<<2)+j;
      Cp[(size_t)r*D_+n]=acc[i][j]+bp[n];
    }
  }
}

// f32 LN
template<int RES>
__global__ __launch_bounds__(256)
void ln_k(const float* __restrict__ x0, const float* __restrict__ resf,
          const float* __restrict__ resb,
          const float* __restrict__ g, const float* __restrict__ b, size_t gboff,
          float* __restrict__ y)
{
  __shared__ float sm[4];
  size_t base = (size_t)blockIdx.x * D_;
  float xv[3]; float s=0.f;
  #pragma unroll
  for (int i=0;i<3;++i){
    int c=threadIdx.x+(i<<8);
    float tv=x0[base+c];
    if (RES==1) tv+=resf[base+c];
    if (RES==2) tv+=resb[base+c];
    xv[i]=tv; s+=tv;
  }
  s = block_sum(s, sm);
  float m = s*(1.0f/768.0f);
  float vs=0.f;
  #pragma unroll
  for (int i=0;i<3;++i){ float d=xv[i]-m; vs+=d*d; }
  vs = block_sum(vs, sm);
  float inv = rsqrtf(vs*(1.0f/768.0f)+1e-5f);
  #pragma unroll
  for (int i=0;i<3;++i){
    int c=threadIdx.x+(i<<8);
    y[base+c]=(xv[i]-m)*inv*(g+gboff)[c]+(b+gboff)[c];
  }
}

__global__ void add_k(const float* __restrict__ a, const float* __restrict__ b, float* __restrict__ c, int n)
{ int i=blockIdx.x*256+threadIdx.x; if (i<n) c[i]=a[i]+b[i]; }

// ===== stage C screen: per row-chunk, exact f32 top-16 via 16 parallel argmax rounds =====
__global__ __launch_bounds__(256)
void topk16_chunk_k(const float* __restrict__ simc, int* __restrict__ cand_id,
                    int off, int chunk, int cn, int ldc)
{
  __shared__ float rs[4];
  __shared__ int   ri[4];
  __shared__ float bs_s;
  __shared__ int   bi_s;
  int b = blockIdx.x, t = threadIdx.x;
  const float* rowp = simc + (size_t)b*ldc;
  float v[KPT_];
  #pragma unroll
  for (int k=0;k<KPT_;++k){
    int j = t + (k<<8);
    v[k] = (j < cn) ? rowp[j] : -1e30f;
  }
  float ps = 1e30f; int pi = -1;   // lexicographic threshold (prev extracted)
  for (int round=0; round<CM2_; ++round){
    float ms = -1e30f; int mi = 0x7fffffff;
    #pragma unroll
    for (int k=0;k<KPT_;++k){
      int j = t + (k<<8);
      float s = v[k];
      bool elig = (s < ps) || (s == ps && j > pi);
      if (elig && (s > ms || (s == ms && j < mi))){ ms = s; mi = j; }
    }
    #pragma unroll
    for (int o=32;o>0;o>>=1){
      float os = __shfl_xor(ms, o); int oi = __shfl_xor(mi, o);
      if (os > ms || (os == ms && oi < mi)){ ms = os; mi = oi; }
    }
    if ((t&63)==0){ rs[t>>6]=ms; ri[t>>6]=mi; }
    __syncthreads();
    if (t==0){
      float gs=rs[0]; int gi=ri[0];
      #pragma unroll
      for (int w=1;w<4;++w) if (rs[w]>gs || (rs[w]==gs && ri[w]<gi)){ gs=rs[w]; gi=ri[w]; }
      bs_s=gs; bi_s=gi;
      cand_id[((size_t)b*NCH2_+chunk)*CM2_+round] = (gi==0x7fffffff) ? 0x7fffffff : off+gi;
    }
    __syncthreads();
    ps = bs_s; pi = bi_s;
  }
}

// ===== f64 rescore, one WAVE per candidate (coalesced ans reads) =====
__global__ __launch_bounds__(256)
void rescore_k(const double* __restrict__ fproj64, const float* __restrict__ ans,
               const int* __restrict__ cand_id,
               const double* __restrict__ inv_fp64, const double* __restrict__ inv_an64,
               int* __restrict__ run_id)
{
  __shared__ double q[D_];
  __shared__ double sc_s[NCH2_*CM2_];
  __shared__ int    id_s[NCH2_*CM2_];
  int b = blockIdx.x, t = threadIdx.x;
  int wave = t>>6, lane = t&63;
  for (int i=t;i<D_;i+=256) q[i]=fproj64[(size_t)b*D_+i];
  __syncthreads();
  for (int c = wave; c < NCH2_*CM2_; c += 4){
    int j = cand_id[(size_t)b*NCH2_*CM2_ + c];
    bool ok = ((unsigned)j < (unsigned)N_);
    double acc = 0.0;
    if (ok){
      const float* ar = ans + (size_t)j*D_;
      #pragma unroll
      for (int k=0;k<12;++k){
        int d = lane + (k<<6);
        acc = fma(q[d], (double)ar[d], acc);
      }
    }
    #pragma unroll
    for (int o=32;o>0;o>>=1) acc += __shfl_xor(acc, o);
    if (lane==0){
      sc_s[c] = ok ? acc*inv_fp64[b]*inv_an64[j] : -1e300;
      id_s[c] = ok ? j : 0x7fffffff;
    }
  }
  __syncthreads();
  if (t==0){
    double gs[10]; int gi[10];
    #pragma unroll
    for (int k=0;k<10;++k){ gs[k]=-1e300; gi[k]=0x7fffffff; }
    for (int i=0;i<NCH2_*CM2_;++i){
      double s=sc_s[i]; int id=id_s[i];
      bool better9 = (s>gs[9]) || (s==gs[9] && id<gi[9]);
      if (!better9) continue;
      int q9=9;
      while (q9>0 && (gs[q9-1]<s || (gs[q9-1]==s && gi[q9-1]>id))){
        gs[q9]=gs[q9-1]; gi[q9]=gi[q9-1]; --q9;
      }
      gs[q9]=s; gi[q9]=id;
    }
    #pragma unroll
    for (int k=0;k<10;++k) run_id[b*10+k]=gi[k];
  }
}

// m4 attention: one thread per (b,h); K/V interleaved in kvh [B*10][1536].
__global__ __launch_bounds__(64)
void attn2_k(const float* __restrict__ qh, const float* __restrict__ kvh,
             float* __restrict__ o)
{
  int idx = blockIdx.x*64 + threadIdx.x;
  if (idx >= B_*8) return;
  int b = idx >> 3, h = idx & 7;
  const float* q = qh + (size_t)b*D_ + h*96;
  float p[10];
  float mx = -1e30f;
  for (int j=0;j<10;++j){
    const float* kr = kvh + ((size_t)(b*10+j))*1536 + h*96;
    float acc=0.f;
    for (int d=0;d<96;++d) acc = fmaf(q[d], kr[d], acc);
    p[j] = acc * 0.10206207261596575f;
    mx = fmaxf(mx, p[j]);
  }
  float sum=0.f;
  for (int j=0;j<10;++j){ p[j]=expf(p[j]-mx); sum+=p[j]; }
  float inv=1.0f/sum;
  for (int d=0;d<96;++d){
    float acc=0.f;
    for (int j=0;j<10;++j) acc = fmaf(p[j]*inv, kvh[((size_t)(b*10+j))*1536 + 768 + h*96 + d], acc);
    o[(size_t)b*D_ + h*96 + d] = acc;
  }
}

extern "C" void kernel_launch(void* const* d_in, const int* in_sizes, int n_in,
                              void* d_out, int out_size, void* d_ws, size_t ws_size,
                              hipStream_t stream)
{
  const float* vis      = (const float*)d_in[0];
  const float* txt      = (const float*)d_in[1];
  const float* ans      = (const float*)d_in[2];
  const float* vqa_in_w = (const float*)d_in[3];
  const float* vqa_in_b = (const float*)d_in[4];
  const float* vqa_out_w= (const float*)d_in[5];
  const float* vqa_out_b= (const float*)d_in[6];
  const float* fproj_w  = (const float*)d_in[7];
  const float* fproj_b  = (const float*)d_in[8];
  const float* fln_g    = (const float*)d_in[9];
  const float* fln_b    = (const float*)d_in[10];
  const float* sim_w    = (const float*)d_in[11];
  const float* sim_b    = (const float*)d_in[12];
  const float* m_in_w   = (const float*)d_in[13];
  const float* m_in_b   = (const float*)d_in[14];
  const float* m_out_w  = (const float*)d_in[15];
  const float* m_out_b  = (const float*)d_in[16];
  const float* ffn_w1   = (const float*)d_in[17];
  const float* ffn_b1   = (const float*)d_in[18];
  const float* ffn_w2   = (const float*)d_in[19];
  const float* ffn_b2   = (const float*)d_in[20];
  const float* ln_g     = (const float*)d_in[21];
  const float* ln_b     = (const float*)d_in[22];
  const float* outp_w   = (const float*)d_in[23];
  const float* outp_b   = (const float*)d_in[24];
  const float* open_w1  = (const float*)d_in[25];
  const float* open_b1  = (const float*)d_in[26];
  const float* open_w2  = (const float*)d_in[27];
  const float* open_b2  = (const float*)d_in[28];
  (void)n_in; (void)out_size;

  if (in_sizes[0]!=B_*D_) return;
  if (in_sizes[1]!=B_*D_) return;
  if (in_sizes[2]!=N_*D_) return;
  if (in_sizes[3]!=3*D_*D_) return;
  if (in_sizes[4]!=3*D_) return;
  if (in_sizes[5]!=D_*D_) return;
  if (in_sizes[7]!=D_*2*D_) return;
  if (in_sizes[9]!=D_) return;
  if (in_sizes[13]!=5*3*D_*D_) return;
  if (in_sizes[14]!=5*3*D_) return;
  if (in_sizes[15]!=5*D_*D_) return;
  if (in_sizes[17]!=4*D_*D_) return;
  if (in_sizes[19]!=4*D_*D_) return;
  if (in_sizes[21]!=4*D_) return;
  if (in_sizes[23]!=D_*D_) return;
  if (in_sizes[25]!=D_*D_) return;
  if (in_sizes[27]!=N_*D_) return;

  const size_t MBc = (size_t)1<<20;
  if (ws_size < 84*MBc) return;
  char* base = (char*)d_ws;
  // ---- phase 1 (f64 selection chain) ----
  double* fusedin64 = (double*)(base + 0);       // [0,12M)
  double* attn_v64  = (double*)(base + 12*MBc);  // [12,18M)
  double* ta64      = (double*)(base + 12*MBc);  // [12,18M) (attn_v64 dead)
  double* fused64   = (double*)(base + 18*MBc);  // [18,24M)
  double* fproj64   = (double*)(base + 60*MBc);  // [60,66M) persists -> rescore
  float*  fproj32   = (float*) (base + 66*MBc);  // [66,69M)
  float*  sim_ch    = (float*) (base + 0);       // [0,51.2M) screen (A/B temps dead)
  double* inv_an64  = (double*)(base + 69*MBc);  // 400KB
  double* inv_fp64  = (double*)(base + 70*MBc);  // 8KB
  float*  inv_an32  = (float*) (base + 71*MBc);  // 200KB
  float*  inv_fp32  = (float*) (base + 72*MBc);  // 4KB
  int*    cand_id   = (int*)   (base + 73*MBc);  // 256KB
  int*    run_id    = (int*)   (base + 78*MBc);  // 40KB (survives into phase 2)
  // ---- phase 2 (f32 residual stream; phase-1 regions dead) ----
  float* kvh  = (float*)(base + 0);              // [0,60M)   m4 K|V
  float* h1   = (float*)(base + 0);              // [0,12M)   FFN (kvh dead)
  float* ta   = (float*)(base + 60*MBc);         // [60,63M)
  float* tb   = (float*)(base + 63*MBc);         // [63,66M)
  float* tc   = (float*)(base + 66*MBc);         // [66,69M)
  float* fz0  = (float*)(base + 66*MBc);         // (tc dead)
  float* td   = (float*)(base + 69*MBc);         // [69,72M)
  float* fz   = (float*)(base + 69*MBc);         // (td dead)
  float* v1   = (float*)(base + 72*MBc);         // [72,75M) m0->m3
  float* o4   = (float*)(base + 72*MBc);         // m4 (v1 dead)
  float* outv = (float*)(base + 72*MBc);         // heads (o4 dead)
  float* t1   = (float*)(base + 75*MBc);         // [75,78M) m1->m2
  float* qh   = (float*)(base + 75*MBc);         // m4 (t1 dead)
  float* g1   = (float*)(base + 75*MBc);         // heads (qh dead)

  dim3 blk(256);
  auto gg = [](int M,int N){ return dim3((unsigned)((N+63)/64),(unsigned)((M+63)/64)); };
  auto g128 = [](int M,int N){ return dim3((unsigned)((N+127)/128),(unsigned)(M/128)); };
  auto ng = [](int M,int N){ return dim3((unsigned)(((size_t)M*N+255)/256)); };
  const size_t IW = (size_t)2304*768, OW = (size_t)768*768;
  const size_t VOFF = (size_t)1536*768, KOFF = (size_t)768*768;
  const int* NORIDX = nullptr;
  const float* NOS = nullptr;

  // ======== phase 1: selection (f64 chain, f32 screen, f64 rescore) ========
  prep64_k<<<ng(B_,D_), blk, 0, stream>>>(vis, fusedin64);
  dgemm_k<1,1><<<gg(B_,D_), blk, 0, stream>>>(vis, vqa_in_w, VOFF, vqa_in_b, 1536, attn_v64, B_, D_, D_, D_);
  dgemm_k<0,1><<<gg(B_,D_), blk, 0, stream>>>(attn_v64, vqa_out_w, 0, vqa_out_b, 0, fusedin64+D_, B_, D_, D_, 2*D_);
  dgemm_k<0,1><<<gg(B_,D_), blk, 0, stream>>>(fusedin64, fproj_w, 0, fproj_b, 0, ta64, B_, D_, 2*D_, D_);
  ln64_k<<<B_, blk, 0, stream>>>(ta64, fln_g, fln_b, fused64);
  dgemm_k<0,1><<<gg(B_,D_), blk, 0, stream>>>(fused64, sim_w, 0, sim_b, 0, fproj64, B_, D_, D_, D_);
  rnorm64w_k<1><<<(N_*64+255)/256, blk, 0, stream>>>(ans, inv_an64, N_);
  rnorm64w_k<0><<<(B_*64+255)/256, blk, 0, stream>>>(fproj64, inv_fp64, B_);
  d2f_k<<<(N_+255)/256, blk, 0, stream>>>(inv_an64, inv_an32, N_);
  d2f_k<<<(B_+255)/256, blk, 0, stream>>>(inv_fp64, inv_fp32, B_);
  d2f_k<<<(B_*D_+255)/256, blk, 0, stream>>>(fproj64, fproj32, B_*D_);
  for (int c=0;c<NCH2_;++c){
    gemm128_k<0,1,0><<<g128(B_,CH2_), blk, 0, stream>>>(fproj32, NORIDX, ans + (size_t)c*CH2_*D_, nullptr, sim_ch, inv_fp32, inv_an32 + c*CH2_, B_, CH2_, D_, CH2_);
    topk16_chunk_k<<<B_, blk, 0, stream>>>(sim_ch, cand_id, c*CH2_, c, CH2_, CH2_);
  }
  rescore_k<<<B_, blk, 0, stream>>>(fproj64, ans, cand_id, inv_fp64, inv_an64, run_id);

  // ======== phase 2: residual stream (f32) ========
  // batched m0/m1 V-projections, then O-projections
  gemm2_k<<<dim3(12,16,2), blk, 0, stream>>>(vis, txt, m_in_w, 0*IW+VOFF, 1*IW+VOFF, m_in_b, 0*2304+1536, 1*2304+1536, ta, tb);
  gemm2_k<<<dim3(12,16,2), blk, 0, stream>>>(ta, tb, m_out_w, 0*OW, 1*OW, m_out_b, 0*768, 1*768, tc, td);
  ln_k<2><<<B_, blk, 0, stream>>>(tc, nullptr, vis, ln_g, ln_b, 0*D_, v1);
  ln_k<2><<<B_, blk, 0, stream>>>(td, nullptr, txt, ln_g, ln_b, 1*D_, t1);
  // batched m2(t1)/m3(v1) V-projections, then O-projections
  gemm2_k<<<dim3(12,16,2), blk, 0, stream>>>(t1, v1, m_in_w, 2*IW+VOFF, 3*IW+VOFF, m_in_b, 2*2304+1536, 3*2304+1536, ta, tb);
  gemm2_k<<<dim3(12,16,2), blk, 0, stream>>>(ta, tb, m_out_w, 2*OW, 3*OW, m_out_b, 2*768, 3*768, tc, td);
  ln_k<1><<<B_, blk, 0, stream>>>(tc, td, nullptr, ln_g, ln_b, 2*D_, fz0);
  // m4: q proj + fused K|V proj over gathered ans rows (128-tile pipelined) + attention
  gemm_k<0,1,0><<<gg(B_,D_), blk, 0, stream>>>(fz0, NORIDX, m_in_w, 4*IW, m_in_b, 4*2304, qh, NOS, NOS, B_, D_, D_, D_);
  gemm128_k<1,0,1><<<g128(B_*K_, 2*D_), blk, 0, stream>>>(ans, run_id, m_in_w + 4*IW + KOFF, m_in_b + 4*2304 + 768, kvh, NOS, NOS, B_*K_, 2*D_, D_, 2*D_);
  attn2_k<<<(B_*8+63)/64, dim3(64), 0, stream>>>(qh, kvh, o4);
  gemm_k<0,1,0><<<gg(B_,D_), blk, 0, stream>>>(o4, NORIDX, m_out_w, 4*OW, m_out_b, 4*768, ta, NOS, NOS, B_, D_, D_, D_);
  ln_k<1><<<B_, blk, 0, stream>>>(fz0, ta, nullptr, ln_g, ln_b, 3*D_, fz);
  // FFN + heads
  gemm_k<0,2,0><<<gg(B_,4*D_), blk, 0, stream>>>(fz, NORIDX, ffn_w1, 0, ffn_b1, 0, h1, NOS, NOS, B_, 4*D_, D_, 4*D_);
  gemm_k<0,1,0><<<gg(B_,D_), blk, 0, stream>>>(h1, NORIDX, ffn_w2, 0, ffn_b2, 0, tb, NOS, NOS, B_, D_, 4*D_, D_);
  add_k<<<ng(B_,D_), blk, 0, stream>>>(fz, tb, ta, B_*D_);
  gemm_k<0,1,0><<<gg(B_,D_), blk, 0, stream>>>(ta, NORIDX, outp_w, 0, outp_b, 0, outv, NOS, NOS, B_, D_, D_, D_);
  gemm_k<0,2,0><<<gg(B_,D_), blk, 0, stream>>>(outv, NORIDX, open_w1, 0, open_b1, 0, g1, NOS, NOS, B_, D_, D_, D_);
  gemm128_k<1,0,0><<<g128(B_,N_), blk, 0, stream>>>(g1, NORIDX, open_w2, open_b2, (float*)d_out, NOS, NOS, B_, N_, D_, N_);
}

// Round 19
// 4192.534 us; speedup vs baseline: 1.1059x; 1.0009x over previous
//
#include <hip/hip_runtime.h>
#include <hip/hip_bf16.h>

#define D_  768
#define B_  1024
#define N_  50000
#define K_  10
#define CH2_ 12500
#define NCH2_ 4
#define CM2_ 16
#define KPT_ 49   // ceil(12500/256)

__device__ __forceinline__ float gelu_f(float x){ return 0.5f*x*(1.0f+erff(x*0.70710678118654752f)); }
__device__ __forceinline__ double gelu_d(double x){ return 0.5*x*(1.0+erf(x*0.707106781186547524400844362105)); }

__device__ __forceinline__ float block_sum(float v, float* sm){
  #pragma unroll
  for (int o=32;o>0;o>>=1) v += __shfl_xor(v,o);
  __syncthreads();
  if ((threadIdx.x&63)==0) sm[threadIdx.x>>6]=v;
  __syncthreads();
  return (sm[0]+sm[1])+(sm[2]+sm[3]);
}
__device__ __forceinline__ double block_sum64(double v, double* sm){
  #pragma unroll
  for (int o=32;o>0;o>>=1) v += __shfl_xor(v,o);
  __syncthreads();
  if ((threadIdx.x&63)==0) sm[threadIdx.x>>6]=v;
  __syncthreads();
  return (sm[0]+sm[1])+(sm[2]+sm[3]);
}

// ============ f64 tiled GEMM (stage A/B): C = A @ W^T + bias ============
template<int ASRC, int EPI>
__global__ __launch_bounds__(256)
void dgemm_k(const void* __restrict__ Ap, const float* __restrict__ Wp, size_t woff,
             const float* __restrict__ biasp, size_t boff, double* __restrict__ Cp,
             int M, int N, int Kd, int ldc)
{
  __shared__ double As[16][64];
  __shared__ double Bs[16][64];
  const int t  = threadIdx.x;
  const int tx = t & 15, ty = t >> 4;
  const int row0 = blockIdx.y << 6, col0 = blockIdx.x << 6;
  const int lr = t >> 2, lk = (t & 3) << 2;
  const int ar = row0 + lr;
  const int wn = col0 + lr;
  const float* Wf = Wp + woff;
  double acc[4][4] = {};
  for (int k0 = 0; k0 < Kd; k0 += 16) {
    double av[4], wv[4];
    if (ar < M) {
      if (ASRC==0){
        const double* a = (const double*)Ap + (size_t)ar*Kd + k0 + lk;
        av[0]=a[0]; av[1]=a[1]; av[2]=a[2]; av[3]=a[3];
      } else {
        float4 v = *(const float4*)((const float*)Ap + (size_t)ar*Kd + k0 + lk);
        av[0]=(double)v.x; av[1]=(double)v.y; av[2]=(double)v.z; av[3]=(double)v.w;
      }
    } else { av[0]=av[1]=av[2]=av[3]=0.0; }
    if (wn < N) {
      float4 v = *(const float4*)(Wf + (size_t)wn*Kd + k0 + lk);
      wv[0]=(double)v.x; wv[1]=(double)v.y; wv[2]=(double)v.z; wv[3]=(double)v.w;
    } else { wv[0]=wv[1]=wv[2]=wv[3]=0.0; }
    #pragma unroll
    for (int u=0;u<4;++u){ As[lk+u][lr]=av[u]; Bs[lk+u][lr]=wv[u]; }
    __syncthreads();
    #pragma unroll
    for (int kk=0;kk<16;++kk){
      double aa[4], bb[4];
      #pragma unroll
      for (int u=0;u<4;++u){ aa[u]=As[kk][(ty<<2)+u]; bb[u]=Bs[kk][(tx<<2)+u]; }
      #pragma unroll
      for (int i=0;i<4;++i)
        #pragma unroll
        for (int j=0;j<4;++j)
          acc[i][j] = fma(aa[i], bb[j], acc[i][j]);
    }
    __syncthreads();
  }
  #pragma unroll
  for (int i=0;i<4;++i){
    int r=row0+(ty<<2)+i; if (r>=M) continue;
    #pragma unroll
    for (int j=0;j<4;++j){
      int n=col0+(tx<<2)+j; if (n>=N) continue;
      double v=acc[i][j];
      if (EPI) v += (double)(biasp+boff)[n];
      Cp[(size_t)r*ldc+n]=v;
    }
  }
}

// f64 LN + gelu (stage B)
__global__ __launch_bounds__(256)
void ln64_k(const double* __restrict__ x0, const float* __restrict__ g,
            const float* __restrict__ b, double* __restrict__ y)
{
  __shared__ double sm[4];
  size_t base = (size_t)blockIdx.x * D_;
  double xv[3]; double s=0.0;
  #pragma unroll
  for (int i=0;i<3;++i){ int c=threadIdx.x+(i<<8); xv[i]=x0[base+c]; s+=xv[i]; }
  s = block_sum64(s, sm);
  double m = s*(1.0/768.0);
  double vs=0.0;
  #pragma unroll
  for (int i=0;i<3;++i){ double d=xv[i]-m; vs+=d*d; }
  vs = block_sum64(vs, sm);
  double inv = 1.0/sqrt(vs*(1.0/768.0)+1e-5);
  #pragma unroll
  for (int i=0;i<3;++i){
    int c=threadIdx.x+(i<<8);
    double o=(xv[i]-m)*inv*(double)g[c]+(double)b[c];
    y[base+c]=gelu_d(o);
  }
}

// f64 inverse row norm, one WAVE per row.  SRC: 0 f64 ws, 1 f32 d_in.
template<int SRC>
__global__ __launch_bounds__(256)
void rnorm64w_k(const void* __restrict__ x, double* __restrict__ invn, int M)
{
  int gw = (blockIdx.x*256 + threadIdx.x) >> 6;
  int lane = threadIdx.x & 63;
  if (gw >= M) return;
  size_t base = (size_t)gw * D_;
  double s = 0.0;
  #pragma unroll
  for (int k=0;k<12;++k){
    double v = (SRC==1) ? (double)((const float*)x)[base+lane+(k<<6)]
                        : ((const double*)x)[base+lane+(k<<6)];
    s = fma(v,v,s);
  }
  #pragma unroll
  for (int o=32;o>0;o>>=1) s += __shfl_xor(s,o);
  if (lane==0) invn[gw] = 1.0/fmax(sqrt(s),1e-12);
}

__global__ void d2f_k(const double* __restrict__ src, float* __restrict__ dst, int n)
{ int i=blockIdx.x*256+threadIdx.x; if (i<n) dst[i]=(float)src[i]; }

__global__ void prep64_k(const float* __restrict__ vis, double* __restrict__ fusedin)
{
  int i = blockIdx.x*256+threadIdx.x;
  if (i >= B_*D_) return;
  int r=i/D_, c=i-r*D_;
  fusedin[(size_t)r*(2*D_)+c]=(double)vis[i];
}

// ============ f32 128x128-tile GEMM, K-tile 32, reg-prefetch ============
// C[M,N] = epi( A[M,Kd] @ W[N,Kd]^T + bias ) (×inva[r]×invw[n]).
// M multiple of 128; Kd multiple of 32.  EPI: 0 none, 1 +bias, 2 +bias+gelu.
// GATHER: logical A-row r reads ans-row ridx[r].
template<int EPI, int SCALE, int GATHER>
__global__ __launch_bounds__(256)
void gemm128_k(const float* __restrict__ Ap, const int* __restrict__ ridx,
               const float* __restrict__ Wp,
               const float* __restrict__ biasp, float* __restrict__ Cp,
               const float* __restrict__ inva, const float* __restrict__ invw,
               int M, int N, int Kd, int ldc)
{
  __shared__ __align__(16) float As[32][128];
  __shared__ __align__(16) float Bs[32][128];
  const int t = threadIdx.x;
  const int tx = t & 15, ty = t >> 4;
  const int row0 = blockIdx.y << 7, col0 = blockIdx.x << 7;
  const int lr = t >> 1, lk16 = (t & 1) << 4;
  int arow = row0 + lr;                       // M multiple of 128 -> valid
  if (GATHER){ int gidx = ridx[arow]; arow = ((unsigned)gidx < (unsigned)N_) ? gidx : 0; }
  const int wrow = col0 + lr;
  const bool wok = (wrow < N);
  const float* aptr = Ap + (size_t)arow*Kd + lk16;
  const float* wptr = Wp + (size_t)(wok ? wrow : 0)*Kd + lk16;
  float acc[8][8] = {};
  float4 z; z.x=z.y=z.z=z.w=0.f;
  float4 a[4], b[4];
  #pragma unroll
  for (int u=0;u<4;++u){
    a[u] = *(const float4*)(aptr + 4*u);
    b[u] = wok ? *(const float4*)(wptr + 4*u) : z;
  }
  const int nt = Kd >> 5;
  for (int it=0; it<nt; ++it){
    #pragma unroll
    for (int u=0;u<4;++u){
      As[lk16+4*u+0][lr]=a[u].x; As[lk16+4*u+1][lr]=a[u].y;
      As[lk16+4*u+2][lr]=a[u].z; As[lk16+4*u+3][lr]=a[u].w;
      Bs[lk16+4*u+0][lr]=b[u].x; Bs[lk16+4*u+1][lr]=b[u].y;
      Bs[lk16+4*u+2][lr]=b[u].z; Bs[lk16+4*u+3][lr]=b[u].w;
    }
    __syncthreads();
    if (it+1 < nt){                           // prefetch next k-tile into regs
      const float* ap = aptr + ((it+1)<<5);
      #pragma unroll
      for (int u=0;u<4;++u) a[u] = *(const float4*)(ap + 4*u);
      if (wok){
        const float* wp = wptr + ((it+1)<<5);
        #pragma unroll
        for (int u=0;u<4;++u) b[u] = *(const float4*)(wp + 4*u);
      }
    }
    #pragma unroll 16
    for (int kk=0; kk<32; ++kk){
      float4 aL = *(const float4*)&As[kk][ty<<2];
      float4 aH = *(const float4*)&As[kk][64 + (ty<<2)];
      float4 bL = *(const float4*)&Bs[kk][tx<<2];
      float4 bH = *(const float4*)&Bs[kk][64 + (tx<<2)];
      float av[8] = {aL.x,aL.y,aL.z,aL.w, aH.x,aH.y,aH.z,aH.w};
      float bv[8] = {bL.x,bL.y,bL.z,bL.w, bH.x,bH.y,bH.z,bH.w};
      #pragma unroll
      for (int i=0;i<8;++i)
        #pragma unroll
        for (int j=0;j<8;++j)
          acc[i][j] = fmaf(av[i], bv[j], acc[i][j]);
    }
    __syncthreads();
  }
  #pragma unroll
  for (int i=0;i<8;++i){
    int r = row0 + ((i<4) ? ((ty<<2)+i) : (64 + (ty<<2) + i - 4));
    float ia = SCALE ? inva[r] : 1.f;
    #pragma unroll
    for (int jh=0;jh<2;++jh){
      int cbase = col0 + ((jh==0) ? (tx<<2) : (64 + (tx<<2)));
      #pragma unroll
      for (int j=0;j<4;++j){
        int c = cbase + j;
        if (c >= N) continue;
        float v = acc[i][jh*4+j];
        if (EPI>=1) v += biasp[c];
        if (EPI==2) v = gelu_f(v);
        if (SCALE) v = v * ia * invw[c];
        Cp[(size_t)r*ldc + c] = v;
      }
    }
  }
}

// ============ f32 tiled GEMM (small shapes) ============
template<int ATY, int EPI, int SCALE>
__global__ __launch_bounds__(256)
void gemm_k(const float* __restrict__ Ap, const int* __restrict__ ridx,
            const float* __restrict__ Wp, size_t woff,
            const float* __restrict__ biasp, size_t boff, float* __restrict__ Cp,
            const float* __restrict__ inva32, const float* __restrict__ invw32,
            int M, int N, int Kd, int ldc)
{
  __shared__ __align__(16) float As[16][64];
  __shared__ __align__(16) float Bs[16][64];
  const int t  = threadIdx.x;
  const int tx = t & 15, ty = t >> 4;
  const int row0 = blockIdx.y << 6, col0 = blockIdx.x << 6;
  const int lr = t >> 2, lk = (t & 3) << 2;
  const int ar = row0 + lr;
  const int wn = col0 + lr;
  const float* Wf = Wp + woff;
  float acc[4][4] = {};
  int arow = ar;
  if (ATY==3 && ar < M){
    arow = ridx[ar];
    if ((unsigned)arow >= (unsigned)N_) arow = 0;
  }
  for (int k0 = 0; k0 < Kd; k0 += 16) {
    float av[4], wv[4];
    if (ar < M) {
      float4 v = *(const float4*)(Ap + (size_t)arow*Kd + k0 + lk);
      av[0]=v.x; av[1]=v.y; av[2]=v.z; av[3]=v.w;
    } else { av[0]=av[1]=av[2]=av[3]=0.f; }
    if (wn < N) {
      float4 v = *(const float4*)(Wf + (size_t)wn*Kd + k0 + lk);
      wv[0]=v.x; wv[1]=v.y; wv[2]=v.z; wv[3]=v.w;
    } else { wv[0]=wv[1]=wv[2]=wv[3]=0.f; }
    #pragma unroll
    for (int u=0;u<4;++u){ As[lk+u][lr]=av[u]; Bs[lk+u][lr]=wv[u]; }
    __syncthreads();
    #pragma unroll
    for (int kk=0;kk<16;++kk){
      float4 a4 = *(const float4*)&As[kk][ty<<2];
      float4 b4 = *(const float4*)&Bs[kk][tx<<2];
      float aa[4]={a4.x,a4.y,a4.z,a4.w};
      float bb[4]={b4.x,b4.y,b4.z,b4.w};
      #pragma unroll
      for (int i=0;i<4;++i)
        #pragma unroll
        for (int j=0;j<4;++j)
          acc[i][j] = fmaf(aa[i], bb[j], acc[i][j]);
    }
    __syncthreads();
  }
  float bv[4];
  #pragma unroll
  for (int j=0;j<4;++j){
    int n=col0+(tx<<2)+j;
    bv[j] = (EPI>=1 && n<N) ? (biasp+boff)[n] : 0.f;
  }
  #pragma unroll
  for (int i=0;i<4;++i){
    int r=row0+(ty<<2)+i; if (r>=M) continue;
    float ia = (SCALE && r<M) ? inva32[r] : 1.f;
    #pragma unroll
    for (int j=0;j<4;++j){
      int n=col0+(tx<<2)+j; if (n>=N) continue;
      float v=acc[i][j]+bv[j];
      if (EPI==2) v=gelu_f(v);
      if (SCALE) v = v * ia * invw32[n];
      Cp[(size_t)r*ldc+n]=v;
    }
  }
}

// ============ z-batched pair GEMM: two independent 1024x768x768 (+bias) ============
__global__ __launch_bounds__(256)
void gemm2_k(const float* __restrict__ A0, const float* __restrict__ A1,
             const float* __restrict__ W, size_t w0, size_t w1,
             const float* __restrict__ bias, size_t bo0, size_t bo1,
             float* __restrict__ C0, float* __restrict__ C1)
{
  const float* Ap = blockIdx.z ? A1 : A0;
  const float* Wf = W + (blockIdx.z ? w1 : w0);
  const float* bp = bias + (blockIdx.z ? bo1 : bo0);
  float* Cp = blockIdx.z ? C1 : C0;
  __shared__ __align__(16) float As[16][64];
  __shared__ __align__(16) float Bs[16][64];
  const int t  = threadIdx.x;
  const int tx = t & 15, ty = t >> 4;
  const int row0 = blockIdx.y << 6, col0 = blockIdx.x << 6;
  const int lr = t >> 2, lk = (t & 3) << 2;
  float acc[4][4] = {};
  for (int k0 = 0; k0 < D_; k0 += 16) {
    float4 va = *(const float4*)(Ap + (size_t)(row0+lr)*D_ + k0 + lk);
    float4 vw = *(const float4*)(Wf + (size_t)(col0+lr)*D_ + k0 + lk);
    As[lk+0][lr]=va.x; As[lk+1][lr]=va.y; As[lk+2][lr]=va.z; As[lk+3][lr]=va.w;
    Bs[lk+0][lr]=vw.x; Bs[lk+1][lr]=vw.y; Bs[lk+2][lr]=vw.z; Bs[lk+3][lr]=vw.w;
    __syncthreads();
    #pragma unroll
    for (int kk=0;kk<16;++kk){
      float4 a4 = *(const float4*)&As[kk][ty<<2];
      float4 b4 = *(const float4*)&Bs[kk][tx<<2];
      float aa[4]={a4.x,a4.y,a4.z,a4.w};
      float bb[4]={b4.x,b4.y,b4.z,b4.w};
      #pragma unroll
      for (int i=0;i<4;++i)
        #pragma unroll
        for (int j=0;j<4;++j)
          acc[i][j] = fmaf(aa[i], bb[j], acc[i][j]);
    }
    __syncthreads();
  }
  #pragma unroll
  for (int i=0;i<4;++i){
    int r=row0+(ty<<2)+i;
    #pragma unroll
    for (int j=0;j<4;++j){
      int n=col0+(tx<<2)+j;
      Cp[(size_t)r*D_+n]=acc[i][j]+bp[n];
    }
  }
}

// f32 LN
template<int RES>
__global__ __launch_bounds__(256)
void ln_k(const float* __restrict__ x0, const float* __restrict__ resf,
          const float* __restrict__ resb,
          const float* __restrict__ g, const float* __restrict__ b, size_t gboff,
          float* __restrict__ y)
{
  __shared__ float sm[4];
  size_t base = (size_t)blockIdx.x * D_;
  float xv[3]; float s=0.f;
  #pragma unroll
  for (int i=0;i<3;++i){
    int c=threadIdx.x+(i<<8);
    float tv=x0[base+c];
    if (RES==1) tv+=resf[base+c];
    if (RES==2) tv+=resb[base+c];
    xv[i]=tv; s+=tv;
  }
  s = block_sum(s, sm);
  float m = s*(1.0f/768.0f);
  float vs=0.f;
  #pragma unroll
  for (int i=0;i<3;++i){ float d=xv[i]-m; vs+=d*d; }
  vs = block_sum(vs, sm);
  float inv = rsqrtf(vs*(1.0f/768.0f)+1e-5f);
  #pragma unroll
  for (int i=0;i<3;++i){
    int c=threadIdx.x+(i<<8);
    y[base+c]=(xv[i]-m)*inv*(g+gboff)[c]+(b+gboff)[c];
  }
}

__global__ void add_k(const float* __restrict__ a, const float* __restrict__ b, float* __restrict__ c, int n)
{ int i=blockIdx.x*256+threadIdx.x; if (i<n) c[i]=a[i]+b[i]; }

// ===== stage C screen: per row-chunk, exact f32 top-16 via 16 parallel argmax rounds =====
__global__ __launch_bounds__(256)
void topk16_chunk_k(const float* __restrict__ simc, int* __restrict__ cand_id,
                    int off, int chunk, int cn, int ldc)
{
  __shared__ float rs[4];
  __shared__ int   ri[4];
  __shared__ float bs_s;
  __shared__ int   bi_s;
  int b = blockIdx.x, t = threadIdx.x;
  const float* rowp = simc + (size_t)b*ldc;
  float v[KPT_];
  #pragma unroll
  for (int k=0;k<KPT_;++k){
    int j = t + (k<<8);
    v[k] = (j < cn) ? rowp[j] : -1e30f;
  }
  float ps = 1e30f; int pi = -1;   // lexicographic threshold (prev extracted)
  for (int round=0; round<CM2_; ++round){
    float ms = -1e30f; int mi = 0x7fffffff;
    #pragma unroll
    for (int k=0;k<KPT_;++k){
      int j = t + (k<<8);
      float s = v[k];
      bool elig = (s < ps) || (s == ps && j > pi);
      if (elig && (s > ms || (s == ms && j < mi))){ ms = s; mi = j; }
    }
    #pragma unroll
    for (int o=32;o>0;o>>=1){
      float os = __shfl_xor(ms, o); int oi = __shfl_xor(mi, o);
      if (os > ms || (os == ms && oi < mi)){ ms = os; mi = oi; }
    }
    if ((t&63)==0){ rs[t>>6]=ms; ri[t>>6]=mi; }
    __syncthreads();
    if (t==0){
      float gs=rs[0]; int gi=ri[0];
      #pragma unroll
      for (int w=1;w<4;++w) if (rs[w]>gs || (rs[w]==gs && ri[w]<gi)){ gs=rs[w]; gi=ri[w]; }
      bs_s=gs; bi_s=gi;
      cand_id[((size_t)b*NCH2_+chunk)*CM2_+round] = (gi==0x7fffffff) ? 0x7fffffff : off+gi;
    }
    __syncthreads();
    ps = bs_s; pi = bi_s;
  }
}

// ===== f64 rescore, one WAVE per candidate (coalesced ans reads) =====
__global__ __launch_bounds__(256)
void rescore_k(const double* __restrict__ fproj64, const float* __restrict__ ans,
               const int* __restrict__ cand_id,
               const double* __restrict__ inv_fp64, const double* __restrict__ inv_an64,
               int* __restrict__ run_id)
{
  __shared__ double q[D_];
  __shared__ double sc_s[NCH2_*CM2_];
  __shared__ int    id_s[NCH2_*CM2_];
  int b = blockIdx.x, t = threadIdx.x;
  int wave = t>>6, lane = t&63;
  for (int i=t;i<D_;i+=256) q[i]=fproj64[(size_t)b*D_+i];
  __syncthreads();
  for (int c = wave; c < NCH2_*CM2_; c += 4){
    int j = cand_id[(size_t)b*NCH2_*CM2_ + c];
    bool ok = ((unsigned)j < (unsigned)N_);
    double acc = 0.0;
    if (ok){
      const float* ar = ans + (size_t)j*D_;
      #pragma unroll
      for (int k=0;k<12;++k){
        int d = lane + (k<<6);
        acc = fma(q[d], (double)ar[d], acc);
      }
    }
    #pragma unroll
    for (int o=32;o>0;o>>=1) acc += __shfl_xor(acc, o);
    if (lane==0){
      sc_s[c] = ok ? acc*inv_fp64[b]*inv_an64[j] : -1e300;
      id_s[c] = ok ? j : 0x7fffffff;
    }
  }
  __syncthreads();
  if (t==0){
    double gs[10]; int gi[10];
    #pragma unroll
    for (int k=0;k<10;++k){ gs[k]=-1e300; gi[k]=0x7fffffff; }
    for (int i=0;i<NCH2_*CM2_;++i){
      double s=sc_s[i]; int id=id_s[i];
      bool better9 = (s>gs[9]) || (s==gs[9] && id<gi[9]);
      if (!better9) continue;
      int q9=9;
      while (q9>0 && (gs[q9-1]<s || (gs[q9-1]==s && gi[q9-1]>id))){
        gs[q9]=gs[q9-1]; gi[q9]=gi[q9-1]; --q9;
      }
      gs[q9]=s; gi[q9]=id;
    }
    #pragma unroll
    for (int k=0;k<10;++k) run_id[b*10+k]=gi[k];
  }
}

// m4 attention: one thread per (b,h); K/V interleaved in kvh [B*10][1536].
__global__ __launch_bounds__(64)
void attn2_k(const float* __restrict__ qh, const float* __restrict__ kvh,
             float* __restrict__ o)
{
  int idx = blockIdx.x*64 + threadIdx.x;
  if (idx >= B_*8) return;
  int b = idx >> 3, h = idx & 7;
  const float* q = qh + (size_t)b*D_ + h*96;
  float p[10];
  float mx = -1e30f;
  for (int j=0;j<10;++j){
    const float* kr = kvh + ((size_t)(b*10+j))*1536 + h*96;
    float acc=0.f;
    for (int d=0;d<96;++d) acc = fmaf(q[d], kr[d], acc);
    p[j] = acc * 0.10206207261596575f;
    mx = fmaxf(mx, p[j]);
  }
  float sum=0.f;
  for (int j=0;j<10;++j){ p[j]=expf(p[j]-mx); sum+=p[j]; }
  float inv=1.0f/sum;
  for (int d=0;d<96;++d){
    float acc=0.f;
    for (int j=0;j<10;++j) acc = fmaf(p[j]*inv, kvh[((size_t)(b*10+j))*1536 + 768 + h*96 + d], acc);
    o[(size_t)b*D_ + h*96 + d] = acc;
  }
}

extern "C" void kernel_launch(void* const* d_in, const int* in_sizes, int n_in,
                              void* d_out, int out_size, void* d_ws, size_t ws_size,
                              hipStream_t stream)
{
  const float* vis      = (const float*)d_in[0];
  const float* txt      = (const float*)d_in[1];
  const float* ans      = (const float*)d_in[2];
  const float* vqa_in_w = (const float*)d_in[3];
  const float* vqa_in_b = (const float*)d_in[4];
  const float* vqa_out_w= (const float*)d_in[5];
  const float* vqa_out_b= (const float*)d_in[6];
  const float* fproj_w  = (const float*)d_in[7];
  const float* fproj_b  = (const float*)d_in[8];
  const float* fln_g    = (const float*)d_in[9];
  const float* fln_b    = (const float*)d_in[10];
  const float* sim_w    = (const float*)d_in[11];
  const float* sim_b    = (const float*)d_in[12];
  const float* m_in_w   = (const float*)d_in[13];
  const float* m_in_b   = (const float*)d_in[14];
  const float* m_out_w  = (const float*)d_in[15];
  const float* m_out_b  = (const float*)d_in[16];
  const float* ffn_w1   = (const float*)d_in[17];
  const float* ffn_b1   = (const float*)d_in[18];
  const float* ffn_w2   = (const float*)d_in[19];
  const float* ffn_b2   = (const float*)d_in[20];
  const float* ln_g     = (const float*)d_in[21];
  const float* ln_b     = (const float*)d_in[22];
  const float* outp_w   = (const float*)d_in[23];
  const float* outp_b   = (const float*)d_in[24];
  const float* open_w1  = (const float*)d_in[25];
  const float* open_b1  = (const float*)d_in[26];
  const float* open_w2  = (const float*)d_in[27];
  const float* open_b2  = (const float*)d_in[28];
  (void)n_in; (void)out_size;

  if (in_sizes[0]!=B_*D_) return;
  if (in_sizes[1]!=B_*D_) return;
  if (in_sizes[2]!=N_*D_) return;
  if (in_sizes[3]!=3*D_*D_) return;
  if (in_sizes[4]!=3*D_) return;
  if (in_sizes[5]!=D_*D_) return;
  if (in_sizes[7]!=D_*2*D_) return;
  if (in_sizes[9]!=D_) return;
  if (in_sizes[13]!=5*3*D_*D_) return;
  if (in_sizes[14]!=5*3*D_) return;
  if (in_sizes[15]!=5*D_*D_) return;
  if (in_sizes[17]!=4*D_*D_) return;
  if (in_sizes[19]!=4*D_*D_) return;
  if (in_sizes[21]!=4*D_) return;
  if (in_sizes[23]!=D_*D_) return;
  if (in_sizes[25]!=D_*D_) return;
  if (in_sizes[27]!=N_*D_) return;

  const size_t MBc = (size_t)1<<20;
  if (ws_size < 84*MBc) return;
  char* base = (char*)d_ws;
  // ---- phase 1 (f64 selection chain) ----
  double* fusedin64 = (double*)(base + 0);       // [0,12M)
  double* attn_v64  = (double*)(base + 12*MBc);  // [12,18M)
  double* ta64      = (double*)(base + 12*MBc);  // [12,18M) (attn_v64 dead)
  double* fused64   = (double*)(base + 18*MBc);  // [18,24M)
  double* fproj64   = (double*)(base + 60*MBc);  // [60,66M) persists -> rescore
  float*  fproj32   = (float*) (base + 66*MBc);  // [66,69M)
  float*  sim_ch    = (float*) (base + 0);       // [0,51.2M) screen (A/B temps dead)
  double* inv_an64  = (double*)(base + 69*MBc);  // 400KB
  double* inv_fp64  = (double*)(base + 70*MBc);  // 8KB
  float*  inv_an32  = (float*) (base + 71*MBc);  // 200KB
  float*  inv_fp32  = (float*) (base + 72*MBc);  // 4KB
  int*    cand_id   = (int*)   (base + 73*MBc);  // 256KB
  int*    run_id    = (int*)   (base + 78*MBc);  // 40KB (survives into phase 2)
  // ---- phase 2 (f32 residual stream; phase-1 regions dead) ----
  float* kvh  = (float*)(base + 0);              // [0,60M)   m4 K|V
  float* h1   = (float*)(base + 0);              // [0,12M)   FFN (kvh dead)
  float* ta   = (float*)(base + 60*MBc);         // [60,63M)
  float* tb   = (float*)(base + 63*MBc);         // [63,66M)
  float* tc   = (float*)(base + 66*MBc);         // [66,69M)
  float* fz0  = (float*)(base + 66*MBc);         // (tc dead)
  float* td   = (float*)(base + 69*MBc);         // [69,72M)
  float* fz   = (float*)(base + 69*MBc);         // (td dead)
  float* v1   = (float*)(base + 72*MBc);         // [72,75M) m0->m3
  float* o4   = (float*)(base + 72*MBc);         // m4 (v1 dead)
  float* outv = (float*)(base + 72*MBc);         // heads (o4 dead)
  float* t1   = (float*)(base + 75*MBc);         // [75,78M) m1->m2
  float* qh   = (float*)(base + 75*MBc);         // m4 (t1 dead)
  float* g1   = (float*)(base + 75*MBc);         // heads (qh dead)

  dim3 blk(256);
  auto gg = [](int M,int N){ return dim3((unsigned)((N+63)/64),(unsigned)((M+63)/64)); };
  auto g128 = [](int M,int N){ return dim3((unsigned)((N+127)/128),(unsigned)(M/128)); };
  auto ng = [](int M,int N){ return dim3((unsigned)(((size_t)M*N+255)/256)); };
  const size_t IW = (size_t)2304*768, OW = (size_t)768*768;
  const size_t VOFF = (size_t)1536*768, KOFF = (size_t)768*768;
  const int* NORIDX = nullptr;
  const float* NOS = nullptr;

  // ======== phase 1: selection (f64 chain, f32 screen, f64 rescore) ========
  prep64_k<<<ng(B_,D_), blk, 0, stream>>>(vis, fusedin64);
  dgemm_k<1,1><<<gg(B_,D_), blk, 0, stream>>>(vis, vqa_in_w, VOFF, vqa_in_b, 1536, attn_v64, B_, D_, D_, D_);
  dgemm_k<0,1><<<gg(B_,D_), blk, 0, stream>>>(attn_v64, vqa_out_w, 0, vqa_out_b, 0, fusedin64+D_, B_, D_, D_, 2*D_);
  dgemm_k<0,1><<<gg(B_,D_), blk, 0, stream>>>(fusedin64, fproj_w, 0, fproj_b, 0, ta64, B_, D_, 2*D_, D_);
  ln64_k<<<B_, blk, 0, stream>>>(ta64, fln_g, fln_b, fused64);
  dgemm_k<0,1><<<gg(B_,D_), blk, 0, stream>>>(fused64, sim_w, 0, sim_b, 0, fproj64, B_, D_, D_, D_);
  rnorm64w_k<1><<<(N_*64+255)/256, blk, 0, stream>>>(ans, inv_an64, N_);
  rnorm64w_k<0><<<(B_*64+255)/256, blk, 0, stream>>>(fproj64, inv_fp64, B_);
  d2f_k<<<(N_+255)/256, blk, 0, stream>>>(inv_an64, inv_an32, N_);
  d2f_k<<<(B_+255)/256, blk, 0, stream>>>(inv_fp64, inv_fp32, B_);
  d2f_k<<<(B_*D_+255)/256, blk, 0, stream>>>(fproj64, fproj32, B_*D_);
  for (int c=0;c<NCH2_;++c){
    gemm128_k<0,1,0><<<g128(B_,CH2_), blk, 0, stream>>>(fproj32, NORIDX, ans + (size_t)c*CH2_*D_, nullptr, sim_ch, inv_fp32, inv_an32 + c*CH2_, B_, CH2_, D_, CH2_);
    topk16_chunk_k<<<B_, blk, 0, stream>>>(sim_ch, cand_id, c*CH2_, c, CH2_, CH2_);
  }
  rescore_k<<<B_, blk, 0, stream>>>(fproj64, ans, cand_id, inv_fp64, inv_an64, run_id);

  // ======== phase 2: residual stream (f32) ========
  gemm2_k<<<dim3(12,16,2), blk, 0, stream>>>(vis, txt, m_in_w, 0*IW+VOFF, 1*IW+VOFF, m_in_b, 0*2304+1536, 1*2304+1536, ta, tb);
  gemm2_k<<<dim3(12,16,2), blk, 0, stream>>>(ta, tb, m_out_w, 0*OW, 1*OW, m_out_b, 0*768, 1*768, tc, td);
  ln_k<2><<<B_, blk, 0, stream>>>(tc, nullptr, vis, ln_g, ln_b, 0*D_, v1);
  ln_k<2><<<B_, blk, 0, stream>>>(td, nullptr, txt, ln_g, ln_b, 1*D_, t1);
  gemm2_k<<<dim3(12,16,2), blk, 0, stream>>>(t1, v1, m_in_w, 2*IW+VOFF, 3*IW+VOFF, m_in_b, 2*2304+1536, 3*2304+1536, ta, tb);
  gemm2_k<<<dim3(12,16,2), blk, 0, stream>>>(ta, tb, m_out_w, 2*OW, 3*OW, m_out_b, 2*768, 3*768, tc, td);
  ln_k<1><<<B_, blk, 0, stream>>>(tc, td, nullptr, ln_g, ln_b, 2*D_, fz0);
  // m4: q proj + fused K|V proj over gathered ans rows (128-tile pipelined) + attention
  gemm_k<0,1,0><<<gg(B_,D_), blk, 0, stream>>>(fz0, NORIDX, m_in_w, 4*IW, m_in_b, 4*2304, qh, NOS, NOS, B_, D_, D_, D_);
  gemm128_k<1,0,1><<<g128(B_*K_, 2*D_), blk, 0, stream>>>(ans, run_id, m_in_w + 4*IW + KOFF, m_in_b + 4*2304 + 768, kvh, NOS, NOS, B_*K_, 2*D_, D_, 2*D_);
  attn2_k<<<(B_*8+63)/64, dim3(64), 0, stream>>>(qh, kvh, o4);
  gemm_k<0,1,0><<<gg(B_,D_), blk, 0, stream>>>(o4, NORIDX, m_out_w, 4*OW, m_out_b, 4*768, ta, NOS, NOS, B_, D_, D_, D_);
  ln_k<1><<<B_, blk, 0, stream>>>(fz0, ta, nullptr, ln_g, ln_b, 3*D_, fz);
  // FFN (w1 via 128-tile with fused gelu) + heads
  gemm128_k<2,0,0><<<g128(B_,4*D_), blk, 0, stream>>>(fz, NORIDX, ffn_w1, ffn_b1, h1, NOS, NOS, B_, 4*D_, D_, 4*D_);
  gemm_k<0,1,0><<<gg(B_,D_), blk, 0, stream>>>(h1, NORIDX, ffn_w2, 0, ffn_b2, 0, tb, NOS, NOS, B_, D_, 4*D_, D_);
  add_k<<<ng(B_,D_), blk, 0, stream>>>(fz, tb, ta, B_*D_);
  gemm_k<0,1,0><<<gg(B_,D_), blk, 0, stream>>>(ta, NORIDX, outp_w, 0, outp_b, 0, outv, NOS, NOS, B_, D_, D_, D_);
  gemm_k<0,2,0><<<gg(B_,D_), blk, 0, stream>>>(outv, NORIDX, open_w1, 0, open_b1, 0, g1, NOS, NOS, B_, D_, D_, D_);
  gemm128_k<1,0,0><<<g128(B_,N_), blk, 0, stream>>>(g1, NORIDX, open_w2, open_b2, (float*)d_out, NOS, NOS, B_, N_, D_, N_);
}

// Round 20
// 4111.754 us; speedup vs baseline: 1.1276x; 1.0196x over previous
//
#include <hip/hip_runtime.h>
#include <hip/hip_bf16.h>

#define D_  768
#define B_  1024
#define N_  50000
#define K_  10
#define CH2_ 12500
#define NCH2_ 4
#define CM2_ 16
#define KPT_ 49   // ceil(12500/256)

__device__ __forceinline__ float gelu_f(float x){ return 0.5f*x*(1.0f+erff(x*0.70710678118654752f)); }
__device__ __forceinline__ double gelu_d(double x){ return 0.5*x*(1.0+erf(x*0.707106781186547524400844362105)); }

__device__ __forceinline__ float block_sum(float v, float* sm){
  #pragma unroll
  for (int o=32;o>0;o>>=1) v += __shfl_xor(v,o);
  __syncthreads();
  if ((threadIdx.x&63)==0) sm[threadIdx.x>>6]=v;
  __syncthreads();
  return (sm[0]+sm[1])+(sm[2]+sm[3]);
}
__device__ __forceinline__ double block_sum64(double v, double* sm){
  #pragma unroll
  for (int o=32;o>0;o>>=1) v += __shfl_xor(v,o);
  __syncthreads();
  if ((threadIdx.x&63)==0) sm[threadIdx.x>>6]=v;
  __syncthreads();
  return (sm[0]+sm[1])+(sm[2]+sm[3]);
}

// ============ f64 tiled GEMM (stage A/B): C = A @ W^T + bias ============
template<int ASRC, int EPI>
__global__ __launch_bounds__(256)
void dgemm_k(const void* __restrict__ Ap, const float* __restrict__ Wp, size_t woff,
             const float* __restrict__ biasp, size_t boff, double* __restrict__ Cp,
             int M, int N, int Kd, int ldc)
{
  __shared__ double As[16][64];
  __shared__ double Bs[16][64];
  const int t  = threadIdx.x;
  const int tx = t & 15, ty = t >> 4;
  const int row0 = blockIdx.y << 6, col0 = blockIdx.x << 6;
  const int lr = t >> 2, lk = (t & 3) << 2;
  const int ar = row0 + lr;
  const int wn = col0 + lr;
  const float* Wf = Wp + woff;
  double acc[4][4] = {};
  for (int k0 = 0; k0 < Kd; k0 += 16) {
    double av[4], wv[4];
    if (ar < M) {
      if (ASRC==0){
        const double* a = (const double*)Ap + (size_t)ar*Kd + k0 + lk;
        av[0]=a[0]; av[1]=a[1]; av[2]=a[2]; av[3]=a[3];
      } else {
        float4 v = *(const float4*)((const float*)Ap + (size_t)ar*Kd + k0 + lk);
        av[0]=(double)v.x; av[1]=(double)v.y; av[2]=(double)v.z; av[3]=(double)v.w;
      }
    } else { av[0]=av[1]=av[2]=av[3]=0.0; }
    if (wn < N) {
      float4 v = *(const float4*)(Wf + (size_t)wn*Kd + k0 + lk);
      wv[0]=(double)v.x; wv[1]=(double)v.y; wv[2]=(double)v.z; wv[3]=(double)v.w;
    } else { wv[0]=wv[1]=wv[2]=wv[3]=0.0; }
    #pragma unroll
    for (int u=0;u<4;++u){ As[lk+u][lr]=av[u]; Bs[lk+u][lr]=wv[u]; }
    __syncthreads();
    #pragma unroll
    for (int kk=0;kk<16;++kk){
      double aa[4], bb[4];
      #pragma unroll
      for (int u=0;u<4;++u){ aa[u]=As[kk][(ty<<2)+u]; bb[u]=Bs[kk][(tx<<2)+u]; }
      #pragma unroll
      for (int i=0;i<4;++i)
        #pragma unroll
        for (int j=0;j<4;++j)
          acc[i][j] = fma(aa[i], bb[j], acc[i][j]);
    }
    __syncthreads();
  }
  #pragma unroll
  for (int i=0;i<4;++i){
    int r=row0+(ty<<2)+i; if (r>=M) continue;
    #pragma unroll
    for (int j=0;j<4;++j){
      int n=col0+(tx<<2)+j; if (n>=N) continue;
      double v=acc[i][j];
      if (EPI) v += (double)(biasp+boff)[n];
      Cp[(size_t)r*ldc+n]=v;
    }
  }
}

// f64 LN + gelu (stage B)
__global__ __launch_bounds__(256)
void ln64_k(const double* __restrict__ x0, const float* __restrict__ g,
            const float* __restrict__ b, double* __restrict__ y)
{
  __shared__ double sm[4];
  size_t base = (size_t)blockIdx.x * D_;
  double xv[3]; double s=0.0;
  #pragma unroll
  for (int i=0;i<3;++i){ int c=threadIdx.x+(i<<8); xv[i]=x0[base+c]; s+=xv[i]; }
  s = block_sum64(s, sm);
  double m = s*(1.0/768.0);
  double vs=0.0;
  #pragma unroll
  for (int i=0;i<3;++i){ double d=xv[i]-m; vs+=d*d; }
  vs = block_sum64(vs, sm);
  double inv = 1.0/sqrt(vs*(1.0/768.0)+1e-5);
  #pragma unroll
  for (int i=0;i<3;++i){
    int c=threadIdx.x+(i<<8);
    double o=(xv[i]-m)*inv*(double)g[c]+(double)b[c];
    y[base+c]=gelu_d(o);
  }
}

// f64 inverse row norm, one WAVE per row.  SRC: 0 f64 ws, 1 f32 d_in.
template<int SRC>
__global__ __launch_bounds__(256)
void rnorm64w_k(const void* __restrict__ x, double* __restrict__ invn, int M)
{
  int gw = (blockIdx.x*256 + threadIdx.x) >> 6;
  int lane = threadIdx.x & 63;
  if (gw >= M) return;
  size_t base = (size_t)gw * D_;
  double s = 0.0;
  #pragma unroll
  for (int k=0;k<12;++k){
    double v = (SRC==1) ? (double)((const float*)x)[base+lane+(k<<6)]
                        : ((const double*)x)[base+lane+(k<<6)];
    s = fma(v,v,s);
  }
  #pragma unroll
  for (int o=32;o>0;o>>=1) s += __shfl_xor(s,o);
  if (lane==0) invn[gw] = 1.0/fmax(sqrt(s),1e-12);
}

__global__ void d2f_k(const double* __restrict__ src, float* __restrict__ dst, int n)
{ int i=blockIdx.x*256+threadIdx.x; if (i<n) dst[i]=(float)src[i]; }

__global__ void prep64_k(const float* __restrict__ vis, double* __restrict__ fusedin)
{
  int i = blockIdx.x*256+threadIdx.x;
  if (i >= B_*D_) return;
  int r=i/D_, c=i-r*D_;
  fusedin[(size_t)r*(2*D_)+c]=(double)vis[i];
}

// ============ f32 128x128-tile GEMM, K-tile 32, reg-prefetch ============
// Block-index remapped: consecutive bids share a W panel (L2 reuse).
// C[M,N] = epi( A[M,Kd] @ W[N,Kd]^T + bias ) (×inva[r]×invw[n]).
// M multiple of 128; Kd multiple of 32.  EPI: 0 none, 1 +bias, 2 +bias+gelu.
// GATHER: logical A-row r reads ans-row ridx[r].
template<int EPI, int SCALE, int GATHER>
__global__ __launch_bounds__(256)
void gemm128_k(const float* __restrict__ Ap, const int* __restrict__ ridx,
               const float* __restrict__ Wp,
               const float* __restrict__ biasp, float* __restrict__ Cp,
               const float* __restrict__ inva, const float* __restrict__ invw,
               int M, int N, int Kd, int ldc)
{
  __shared__ __align__(16) float As[32][128];
  __shared__ __align__(16) float Bs[32][128];
  const int t = threadIdx.x;
  const int tx = t & 15, ty = t >> 4;
  const int bid = blockIdx.y * gridDim.x + blockIdx.x;
  const int row0 = (bid % gridDim.y) << 7;      // A panel cycles fastest
  const int col0 = (bid / gridDim.y) << 7;      // consecutive bids share W panel
  const int lr = t >> 1, lk16 = (t & 1) << 4;
  int arow = row0 + lr;                       // M multiple of 128 -> valid
  if (GATHER){ int gidx = ridx[arow]; arow = ((unsigned)gidx < (unsigned)N_) ? gidx : 0; }
  const int wrow = col0 + lr;
  const bool wok = (wrow < N);
  const float* aptr = Ap + (size_t)arow*Kd + lk16;
  const float* wptr = Wp + (size_t)(wok ? wrow : 0)*Kd + lk16;
  float acc[8][8] = {};
  float4 z; z.x=z.y=z.z=z.w=0.f;
  float4 a[4], b[4];
  #pragma unroll
  for (int u=0;u<4;++u){
    a[u] = *(const float4*)(aptr + 4*u);
    b[u] = wok ? *(const float4*)(wptr + 4*u) : z;
  }
  const int nt = Kd >> 5;
  for (int it=0; it<nt; ++it){
    #pragma unroll
    for (int u=0;u<4;++u){
      As[lk16+4*u+0][lr]=a[u].x; As[lk16+4*u+1][lr]=a[u].y;
      As[lk16+4*u+2][lr]=a[u].z; As[lk16+4*u+3][lr]=a[u].w;
      Bs[lk16+4*u+0][lr]=b[u].x; Bs[lk16+4*u+1][lr]=b[u].y;
      Bs[lk16+4*u+2][lr]=b[u].z; Bs[lk16+4*u+3][lr]=b[u].w;
    }
    __syncthreads();
    if (it+1 < nt){                           // prefetch next k-tile into regs
      const float* ap = aptr + ((it+1)<<5);
      #pragma unroll
      for (int u=0;u<4;++u) a[u] = *(const float4*)(ap + 4*u);
      if (wok){
        const float* wp = wptr + ((it+1)<<5);
        #pragma unroll
        for (int u=0;u<4;++u) b[u] = *(const float4*)(wp + 4*u);
      }
    }
    #pragma unroll 16
    for (int kk=0; kk<32; ++kk){
      float4 aL = *(const float4*)&As[kk][ty<<2];
      float4 aH = *(const float4*)&As[kk][64 + (ty<<2)];
      float4 bL = *(const float4*)&Bs[kk][tx<<2];
      float4 bH = *(const float4*)&Bs[kk][64 + (tx<<2)];
      float av[8] = {aL.x,aL.y,aL.z,aL.w, aH.x,aH.y,aH.z,aH.w};
      float bv[8] = {bL.x,bL.y,bL.z,bL.w, bH.x,bH.y,bH.z,bH.w};
      #pragma unroll
      for (int i=0;i<8;++i)
        #pragma unroll
        for (int j=0;j<8;++j)
          acc[i][j] = fmaf(av[i], bv[j], acc[i][j]);
    }
    __syncthreads();
  }
  #pragma unroll
  for (int i=0;i<8;++i){
    int r = row0 + ((i<4) ? ((ty<<2)+i) : (64 + (ty<<2) + i - 4));
    float ia = SCALE ? inva[r] : 1.f;
    #pragma unroll
    for (int jh=0;jh<2;++jh){
      int cbase = col0 + ((jh==0) ? (tx<<2) : (64 + (tx<<2)));
      #pragma unroll
      for (int j=0;j<4;++j){
        int c = cbase + j;
        if (c >= N) continue;
        float v = acc[i][jh*4+j];
        if (EPI>=1) v += biasp[c];
        if (EPI==2) v = gelu_f(v);
        if (SCALE) v = v * ia * invw[c];
        Cp[(size_t)r*ldc + c] = v;
      }
    }
  }
}

// ============ f32 tiled GEMM (small shapes) ============
template<int ATY, int EPI, int SCALE>
__global__ __launch_bounds__(256)
void gemm_k(const float* __restrict__ Ap, const int* __restrict__ ridx,
            const float* __restrict__ Wp, size_t woff,
            const float* __restrict__ biasp, size_t boff, float* __restrict__ Cp,
            const float* __restrict__ inva32, const float* __restrict__ invw32,
            int M, int N, int Kd, int ldc)
{
  __shared__ __align__(16) float As[16][64];
  __shared__ __align__(16) float Bs[16][64];
  const int t  = threadIdx.x;
  const int tx = t & 15, ty = t >> 4;
  const int row0 = blockIdx.y << 6, col0 = blockIdx.x << 6;
  const int lr = t >> 2, lk = (t & 3) << 2;
  const int ar = row0 + lr;
  const int wn = col0 + lr;
  const float* Wf = Wp + woff;
  float acc[4][4] = {};
  int arow = ar;
  if (ATY==3 && ar < M){
    arow = ridx[ar];
    if ((unsigned)arow >= (unsigned)N_) arow = 0;
  }
  for (int k0 = 0; k0 < Kd; k0 += 16) {
    float av[4], wv[4];
    if (ar < M) {
      float4 v = *(const float4*)(Ap + (size_t)arow*Kd + k0 + lk);
      av[0]=v.x; av[1]=v.y; av[2]=v.z; av[3]=v.w;
    } else { av[0]=av[1]=av[2]=av[3]=0.f; }
    if (wn < N) {
      float4 v = *(const float4*)(Wf + (size_t)wn*Kd + k0 + lk);
      wv[0]=v.x; wv[1]=v.y; wv[2]=v.z; wv[3]=v.w;
    } else { wv[0]=wv[1]=wv[2]=wv[3]=0.f; }
    #pragma unroll
    for (int u=0;u<4;++u){ As[lk+u][lr]=av[u]; Bs[lk+u][lr]=wv[u]; }
    __syncthreads();
    #pragma unroll
    for (int kk=0;kk<16;++kk){
      float4 a4 = *(const float4*)&As[kk][ty<<2];
      float4 b4 = *(const float4*)&Bs[kk][tx<<2];
      float aa[4]={a4.x,a4.y,a4.z,a4.w};
      float bb[4]={b4.x,b4.y,b4.z,b4.w};
      #pragma unroll
      for (int i=0;i<4;++i)
        #pragma unroll
        for (int j=0;j<4;++j)
          acc[i][j] = fmaf(aa[i], bb[j], acc[i][j]);
    }
    __syncthreads();
  }
  float bv[4];
  #pragma unroll
  for (int j=0;j<4;++j){
    int n=col0+(tx<<2)+j;
    bv[j] = (EPI>=1 && n<N) ? (biasp+boff)[n] : 0.f;
  }
  #pragma unroll
  for (int i=0;i<4;++i){
    int r=row0+(ty<<2)+i; if (r>=M) continue;
    float ia = (SCALE && r<M) ? inva32[r] : 1.f;
    #pragma unroll
    for (int j=0;j<4;++j){
      int n=col0+(tx<<2)+j; if (n>=N) continue;
      float v=acc[i][j]+bv[j];
      if (EPI==2) v=gelu_f(v);
      if (SCALE) v = v * ia * invw32[n];
      Cp[(size_t)r*ldc+n]=v;
    }
  }
}

// ============ split-K GEMM for FFN2: P[z] = A[:, z*768:(z+1)*768] @ W[:, z*768:..]^T ============
// A [1024][3072], W [768][3072], P 4x[1024][768].  blockIdx.z = split.
__global__ __launch_bounds__(256)
void gemmsk_k(const float* __restrict__ A, const float* __restrict__ W,
              float* __restrict__ P)
{
  const int s = blockIdx.z;
  const float* Ap = A + s*768;
  const float* Wf = W + s*768;
  float* Cp = P + (size_t)s*B_*D_;
  __shared__ __align__(16) float As[16][64];
  __shared__ __align__(16) float Bs[16][64];
  const int t  = threadIdx.x;
  const int tx = t & 15, ty = t >> 4;
  const int row0 = blockIdx.y << 6, col0 = blockIdx.x << 6;
  const int lr = t >> 2, lk = (t & 3) << 2;
  float acc[4][4] = {};
  for (int k0 = 0; k0 < 768; k0 += 16) {
    float4 va = *(const float4*)(Ap + (size_t)(row0+lr)*3072 + k0 + lk);
    float4 vw = *(const float4*)(Wf + (size_t)(col0+lr)*3072 + k0 + lk);
    As[lk+0][lr]=va.x; As[lk+1][lr]=va.y; As[lk+2][lr]=va.z; As[lk+3][lr]=va.w;
    Bs[lk+0][lr]=vw.x; Bs[lk+1][lr]=vw.y; Bs[lk+2][lr]=vw.z; Bs[lk+3][lr]=vw.w;
    __syncthreads();
    #pragma unroll
    for (int kk=0;kk<16;++kk){
      float4 a4 = *(const float4*)&As[kk][ty<<2];
      float4 b4 = *(const float4*)&Bs[kk][tx<<2];
      float aa[4]={a4.x,a4.y,a4.z,a4.w};
      float bb[4]={b4.x,b4.y,b4.z,b4.w};
      #pragma unroll
      for (int i=0;i<4;++i)
        #pragma unroll
        for (int j=0;j<4;++j)
          acc[i][j] = fmaf(aa[i], bb[j], acc[i][j]);
    }
    __syncthreads();
  }
  #pragma unroll
  for (int i=0;i<4;++i){
    int r=row0+(ty<<2)+i;
    #pragma unroll
    for (int j=0;j<4;++j){
      int n=col0+(tx<<2)+j;
      Cp[(size_t)r*D_+n]=acc[i][j];
    }
  }
}

// ta = fz + b2 + sum_{s} P[s]  (fixed order -> deterministic)
__global__ void sum4_k(const float* __restrict__ P, const float* __restrict__ fz,
                       const float* __restrict__ b2, float* __restrict__ out)
{
  int i = blockIdx.x*256 + threadIdx.x;
  if (i >= B_*D_) return;
  int c = i % D_;
  const int SZ = B_*D_;
  float v = (P[i] + P[i+SZ]) + (P[i+2*SZ] + P[i+3*SZ]);
  out[i] = fz[i] + (v + b2[c]);
}

// ============ z-batched pair GEMM: two independent 1024x768x768 (+bias) ============
__global__ __launch_bounds__(256)
void gemm2_k(const float* __restrict__ A0, const float* __restrict__ A1,
             const float* __restrict__ W, size_t w0, size_t w1,
             const float* __restrict__ bias, size_t bo0, size_t bo1,
             float* __restrict__ C0, float* __restrict__ C1)
{
  const float* Ap = blockIdx.z ? A1 : A0;
  const float* Wf = W + (blockIdx.z ? w1 : w0);
  const float* bp = bias + (blockIdx.z ? bo1 : bo0);
  float* Cp = blockIdx.z ? C1 : C0;
  __shared__ __align__(16) float As[16][64];
  __shared__ __align__(16) float Bs[16][64];
  const int t  = threadIdx.x;
  const int tx = t & 15, ty = t >> 4;
  const int row0 = blockIdx.y << 6, col0 = blockIdx.x << 6;
  const int lr = t >> 2, lk = (t & 3) << 2;
  float acc[4][4] = {};
  for (int k0 = 0; k0 < D_; k0 += 16) {
    float4 va = *(const float4*)(Ap + (size_t)(row0+lr)*D_ + k0 + lk);
    float4 vw = *(const float4*)(Wf + (size_t)(col0+lr)*D_ + k0 + lk);
    As[lk+0][lr]=va.x; As[lk+1][lr]=va.y; As[lk+2][lr]=va.z; As[lk+3][lr]=va.w;
    Bs[lk+0][lr]=vw.x; Bs[lk+1][lr]=vw.y; Bs[lk+2][lr]=vw.z; Bs[lk+3][lr]=vw.w;
    __syncthreads();
    #pragma unroll
    for (int kk=0;kk<16;++kk){
      float4 a4 = *(const float4*)&As[kk][ty<<2];
      float4 b4 = *(const float4*)&Bs[kk][tx<<2];
      float aa[4]={a4.x,a4.y,a4.z,a4.w};
      float bb[4]={b4.x,b4.y,b4.z,b4.w};
      #pragma unroll
      for (int i=0;i<4;++i)
        #pragma unroll
        for (int j=0;j<4;++j)
          acc[i][j] = fmaf(aa[i], bb[j], acc[i][j]);
    }
    __syncthreads();
  }
  #pragma unroll
  for (int i=0;i<4;++i){
    int r=row0+(ty<<2)+i;
    #pragma unroll
    for (int j=0;j<4;++j){
      int n=col0+(tx<<2)+j;
      Cp[(size_t)r*D_+n]=acc[i][j]+bp[n];
    }
  }
}

// f32 LN
template<int RES>
__global__ __launch_bounds__(256)
void ln_k(const float* __restrict__ x0, const float* __restrict__ resf,
          const float* __restrict__ resb,
          const float* __restrict__ g, const float* __restrict__ b, size_t gboff,
          float* __restrict__ y)
{
  __shared__ float sm[4];
  size_t base = (size_t)blockIdx.x * D_;
  float xv[3]; float s=0.f;
  #pragma unroll
  for (int i=0;i<3;++i){
    int c=threadIdx.x+(i<<8);
    float tv=x0[base+c];
    if (RES==1) tv+=resf[base+c];
    if (RES==2) tv+=resb[base+c];
    xv[i]=tv; s+=tv;
  }
  s = block_sum(s, sm);
  float m = s*(1.0f/768.0f);
  float vs=0.f;
  #pragma unroll
  for (int i=0;i<3;++i){ float d=xv[i]-m; vs+=d*d; }
  vs = block_sum(vs, sm);
  float inv = rsqrtf(vs*(1.0f/768.0f)+1e-5f);
  #pragma unroll
  for (int i=0;i<3;++i){
    int c=threadIdx.x+(i<<8);
    y[base+c]=(xv[i]-m)*inv*(g+gboff)[c]+(b+gboff)[c];
  }
}

__global__ void add_k(const float* __restrict__ a, const float* __restrict__ b, float* __restrict__ c, int n)
{ int i=blockIdx.x*256+threadIdx.x; if (i<n) c[i]=a[i]+b[i]; }

// ===== stage C screen: per row-chunk, exact f32 top-16 via 16 parallel argmax rounds =====
__global__ __launch_bounds__(256)
void topk16_chunk_k(const float* __restrict__ simc, int* __restrict__ cand_id,
                    int off, int chunk, int cn, int ldc)
{
  __shared__ float rs[4];
  __shared__ int   ri[4];
  __shared__ float bs_s;
  __shared__ int   bi_s;
  int b = blockIdx.x, t = threadIdx.x;
  const float* rowp = simc + (size_t)b*ldc;
  float v[KPT_];
  #pragma unroll
  for (int k=0;k<KPT_;++k){
    int j = t + (k<<8);
    v[k] = (j < cn) ? rowp[j] : -1e30f;
  }
  float ps = 1e30f; int pi = -1;   // lexicographic threshold (prev extracted)
  for (int round=0; round<CM2_; ++round){
    float ms = -1e30f; int mi = 0x7fffffff;
    #pragma unroll
    for (int k=0;k<KPT_;++k){
      int j = t + (k<<8);
      float s = v[k];
      bool elig = (s < ps) || (s == ps && j > pi);
      if (elig && (s > ms || (s == ms && j < mi))){ ms = s; mi = j; }
    }
    #pragma unroll
    for (int o=32;o>0;o>>=1){
      float os = __shfl_xor(ms, o); int oi = __shfl_xor(mi, o);
      if (os > ms || (os == ms && oi < mi)){ ms = os; mi = oi; }
    }
    if ((t&63)==0){ rs[t>>6]=ms; ri[t>>6]=mi; }
    __syncthreads();
    if (t==0){
      float gs=rs[0]; int gi=ri[0];
      #pragma unroll
      for (int w=1;w<4;++w) if (rs[w]>gs || (rs[w]==gs && ri[w]<gi)){ gs=rs[w]; gi=ri[w]; }
      bs_s=gs; bi_s=gi;
      cand_id[((size_t)b*NCH2_+chunk)*CM2_+round] = (gi==0x7fffffff) ? 0x7fffffff : off+gi;
    }
    __syncthreads();
    ps = bs_s; pi = bi_s;
  }
}

// ===== f64 rescore, one WAVE per candidate (coalesced ans reads) =====
__global__ __launch_bounds__(256)
void rescore_k(const double* __restrict__ fproj64, const float* __restrict__ ans,
               const int* __restrict__ cand_id,
               const double* __restrict__ inv_fp64, const double* __restrict__ inv_an64,
               int* __restrict__ run_id)
{
  __shared__ double q[D_];
  __shared__ double sc_s[NCH2_*CM2_];
  __shared__ int    id_s[NCH2_*CM2_];
  int b = blockIdx.x, t = threadIdx.x;
  int wave = t>>6, lane = t&63;
  for (int i=t;i<D_;i+=256) q[i]=fproj64[(size_t)b*D_+i];
  __syncthreads();
  for (int c = wave; c < NCH2_*CM2_; c += 4){
    int j = cand_id[(size_t)b*NCH2_*CM2_ + c];
    bool ok = ((unsigned)j < (unsigned)N_);
    double acc = 0.0;
    if (ok){
      const float* ar = ans + (size_t)j*D_;
      #pragma unroll
      for (int k=0;k<12;++k){
        int d = lane + (k<<6);
        acc = fma(q[d], (double)ar[d], acc);
      }
    }
    #pragma unroll
    for (int o=32;o>0;o>>=1) acc += __shfl_xor(acc, o);
    if (lane==0){
      sc_s[c] = ok ? acc*inv_fp64[b]*inv_an64[j] : -1e300;
      id_s[c] = ok ? j : 0x7fffffff;
    }
  }
  __syncthreads();
  if (t==0){
    double gs[10]; int gi[10];
    #pragma unroll
    for (int k=0;k<10;++k){ gs[k]=-1e300; gi[k]=0x7fffffff; }
    for (int i=0;i<NCH2_*CM2_;++i){
      double s=sc_s[i]; int id=id_s[i];
      bool better9 = (s>gs[9]) || (s==gs[9] && id<gi[9]);
      if (!better9) continue;
      int q9=9;
      while (q9>0 && (gs[q9-1]<s || (gs[q9-1]==s && gi[q9-1]>id))){
        gs[q9]=gs[q9-1]; gi[q9]=gi[q9-1]; --q9;
      }
      gs[q9]=s; gi[q9]=id;
    }
    #pragma unroll
    for (int k=0;k<10;++k) run_id[b*10+k]=gi[k];
  }
}

// m4 attention: one thread per (b,h); K/V interleaved in kvh [B*10][1536].
__global__ __launch_bounds__(64)
void attn2_k(const float* __restrict__ qh, const float* __restrict__ kvh,
             float* __restrict__ o)
{
  int idx = blockIdx.x*64 + threadIdx.x;
  if (idx >= B_*8) return;
  int b = idx >> 3, h = idx & 7;
  const float* q = qh + (size_t)b*D_ + h*96;
  float p[10];
  float mx = -1e30f;
  for (int j=0;j<10;++j){
    const float* kr = kvh + ((size_t)(b*10+j))*1536 + h*96;
    float acc=0.f;
    for (int d=0;d<96;++d) acc = fmaf(q[d], kr[d], acc);
    p[j] = acc * 0.10206207261596575f;
    mx = fmaxf(mx, p[j]);
  }
  float sum=0.f;
  for (int j=0;j<10;++j){ p[j]=expf(p[j]-mx); sum+=p[j]; }
  float inv=1.0f/sum;
  for (int d=0;d<96;++d){
    float acc=0.f;
    for (int j=0;j<10;++j) acc = fmaf(p[j]*inv, kvh[((size_t)(b*10+j))*1536 + 768 + h*96 + d], acc);
    o[(size_t)b*D_ + h*96 + d] = acc;
  }
}

extern "C" void kernel_launch(void* const* d_in, const int* in_sizes, int n_in,
                              void* d_out, int out_size, void* d_ws, size_t ws_size,
                              hipStream_t stream)
{
  const float* vis      = (const float*)d_in[0];
  const float* txt      = (const float*)d_in[1];
  const float* ans      = (const float*)d_in[2];
  const float* vqa_in_w = (const float*)d_in[3];
  const float* vqa_in_b = (const float*)d_in[4];
  const float* vqa_out_w= (const float*)d_in[5];
  const float* vqa_out_b= (const float*)d_in[6];
  const float* fproj_w  = (const float*)d_in[7];
  const float* fproj_b  = (const float*)d_in[8];
  const float* fln_g    = (const float*)d_in[9];
  const float* fln_b    = (const float*)d_in[10];
  const float* sim_w    = (const float*)d_in[11];
  const float* sim_b    = (const float*)d_in[12];
  const float* m_in_w   = (const float*)d_in[13];
  const float* m_in_b   = (const float*)d_in[14];
  const float* m_out_w  = (const float*)d_in[15];
  const float* m_out_b  = (const float*)d_in[16];
  const float* ffn_w1   = (const float*)d_in[17];
  const float* ffn_b1   = (const float*)d_in[18];
  const float* ffn_w2   = (const float*)d_in[19];
  const float* ffn_b2   = (const float*)d_in[20];
  const float* ln_g     = (const float*)d_in[21];
  const float* ln_b     = (const float*)d_in[22];
  const float* outp_w   = (const float*)d_in[23];
  const float* outp_b   = (const float*)d_in[24];
  const float* open_w1  = (const float*)d_in[25];
  const float* open_b1  = (const float*)d_in[26];
  const float* open_w2  = (const float*)d_in[27];
  const float* open_b2  = (const float*)d_in[28];
  (void)n_in; (void)out_size;

  if (in_sizes[0]!=B_*D_) return;
  if (in_sizes[1]!=B_*D_) return;
  if (in_sizes[2]!=N_*D_) return;
  if (in_sizes[3]!=3*D_*D_) return;
  if (in_sizes[4]!=3*D_) return;
  if (in_sizes[5]!=D_*D_) return;
  if (in_sizes[7]!=D_*2*D_) return;
  if (in_sizes[9]!=D_) return;
  if (in_sizes[13]!=5*3*D_*D_) return;
  if (in_sizes[14]!=5*3*D_) return;
  if (in_sizes[15]!=5*D_*D_) return;
  if (in_sizes[17]!=4*D_*D_) return;
  if (in_sizes[19]!=4*D_*D_) return;
  if (in_sizes[21]!=4*D_) return;
  if (in_sizes[23]!=D_*D_) return;
  if (in_sizes[25]!=D_*D_) return;
  if (in_sizes[27]!=N_*D_) return;

  const size_t MBc = (size_t)1<<20;
  if (ws_size < 84*MBc) return;
  char* base = (char*)d_ws;
  // ---- phase 1 (f64 selection chain) ----
  double* fusedin64 = (double*)(base + 0);       // [0,12M)
  double* attn_v64  = (double*)(base + 12*MBc);  // [12,18M)
  double* ta64      = (double*)(base + 12*MBc);  // [12,18M) (attn_v64 dead)
  double* fused64   = (double*)(base + 18*MBc);  // [18,24M)
  double* fproj64   = (double*)(base + 60*MBc);  // [60,66M) persists -> rescore
  float*  fproj32   = (float*) (base + 66*MBc);  // [66,69M)
  float*  sim_ch    = (float*) (base + 0);       // [0,51.2M) screen (A/B temps dead)
  double* inv_an64  = (double*)(base + 69*MBc);  // 400KB
  double* inv_fp64  = (double*)(base + 70*MBc);  // 8KB
  float*  inv_an32  = (float*) (base + 71*MBc);  // 200KB
  float*  inv_fp32  = (float*) (base + 72*MBc);  // 4KB
  int*    cand_id   = (int*)   (base + 73*MBc);  // 256KB
  int*    run_id    = (int*)   (base + 78*MBc);  // 40KB (survives into phase 2)
  // ---- phase 2 (f32 residual stream; phase-1 regions dead) ----
  float* kvh  = (float*)(base + 0);              // [0,60M)   m4 K|V
  float* h1   = (float*)(base + 0);              // [0,12M)   FFN (kvh dead)
  float* pK   = (float*)(base + 12*MBc);         // [12,24M)  FFN2 split-K partials
  float* ta   = (float*)(base + 60*MBc);         // [60,63M)
  float* tb   = (float*)(base + 63*MBc);         // [63,66M)
  float* tc   = (float*)(base + 66*MBc);         // [66,69M)
  float* fz0  = (float*)(base + 66*MBc);         // (tc dead)
  float* td   = (float*)(base + 69*MBc);         // [69,72M)
  float* fz   = (float*)(base + 69*MBc);         // (td dead)
  float* v1   = (float*)(base + 72*MBc);         // [72,75M) m0->m3
  float* o4   = (float*)(base + 72*MBc);         // m4 (v1 dead)
  float* outv = (float*)(base + 72*MBc);         // heads (o4 dead)
  float* t1   = (float*)(base + 75*MBc);         // [75,78M) m1->m2
  float* qh   = (float*)(base + 75*MBc);         // m4 (t1 dead)
  float* g1   = (float*)(base + 75*MBc);         // heads (qh dead)

  dim3 blk(256);
  auto gg = [](int M,int N){ return dim3((unsigned)((N+63)/64),(unsigned)((M+63)/64)); };
  auto g128 = [](int M,int N){ return dim3((unsigned)((N+127)/128),(unsigned)(M/128)); };
  auto ng = [](int M,int N){ return dim3((unsigned)(((size_t)M*N+255)/256)); };
  const size_t IW = (size_t)2304*768, OW = (size_t)768*768;
  const size_t VOFF = (size_t)1536*768, KOFF = (size_t)768*768;
  const int* NORIDX = nullptr;
  const float* NOS = nullptr;

  // ======== phase 1: selection (f64 chain, f32 screen, f64 rescore) ========
  prep64_k<<<ng(B_,D_), blk, 0, stream>>>(vis, fusedin64);
  dgemm_k<1,1><<<gg(B_,D_), blk, 0, stream>>>(vis, vqa_in_w, VOFF, vqa_in_b, 1536, attn_v64, B_, D_, D_, D_);
  dgemm_k<0,1><<<gg(B_,D_), blk, 0, stream>>>(attn_v64, vqa_out_w, 0, vqa_out_b, 0, fusedin64+D_, B_, D_, D_, 2*D_);
  dgemm_k<0,1><<<gg(B_,D_), blk, 0, stream>>>(fusedin64, fproj_w, 0, fproj_b, 0, ta64, B_, D_, 2*D_, D_);
  ln64_k<<<B_, blk, 0, stream>>>(ta64, fln_g, fln_b, fused64);
  dgemm_k<0,1><<<gg(B_,D_), blk, 0, stream>>>(fused64, sim_w, 0, sim_b, 0, fproj64, B_, D_, D_, D_);
  rnorm64w_k<1><<<(N_*64+255)/256, blk, 0, stream>>>(ans, inv_an64, N_);
  rnorm64w_k<0><<<(B_*64+255)/256, blk, 0, stream>>>(fproj64, inv_fp64, B_);
  d2f_k<<<(N_+255)/256, blk, 0, stream>>>(inv_an64, inv_an32, N_);
  d2f_k<<<(B_+255)/256, blk, 0, stream>>>(inv_fp64, inv_fp32, B_);
  d2f_k<<<(B_*D_+255)/256, blk, 0, stream>>>(fproj64, fproj32, B_*D_);
  for (int c=0;c<NCH2_;++c){
    gemm128_k<0,1,0><<<g128(B_,CH2_), blk, 0, stream>>>(fproj32, NORIDX, ans + (size_t)c*CH2_*D_, nullptr, sim_ch, inv_fp32, inv_an32 + c*CH2_, B_, CH2_, D_, CH2_);
    topk16_chunk_k<<<B_, blk, 0, stream>>>(sim_ch, cand_id, c*CH2_, c, CH2_, CH2_);
  }
  rescore_k<<<B_, blk, 0, stream>>>(fproj64, ans, cand_id, inv_fp64, inv_an64, run_id);

  // ======== phase 2: residual stream (f32) ========
  gemm2_k<<<dim3(12,16,2), blk, 0, stream>>>(vis, txt, m_in_w, 0*IW+VOFF, 1*IW+VOFF, m_in_b, 0*2304+1536, 1*2304+1536, ta, tb);
  gemm2_k<<<dim3(12,16,2), blk, 0, stream>>>(ta, tb, m_out_w, 0*OW, 1*OW, m_out_b, 0*768, 1*768, tc, td);
  ln_k<2><<<B_, blk, 0, stream>>>(tc, nullptr, vis, ln_g, ln_b, 0*D_, v1);
  ln_k<2><<<B_, blk, 0, stream>>>(td, nullptr, txt, ln_g, ln_b, 1*D_, t1);
  gemm2_k<<<dim3(12,16,2), blk, 0, stream>>>(t1, v1, m_in_w, 2*IW+VOFF, 3*IW+VOFF, m_in_b, 2*2304+1536, 3*2304+1536, ta, tb);
  gemm2_k<<<dim3(12,16,2), blk, 0, stream>>>(ta, tb, m_out_w, 2*OW, 3*OW, m_out_b, 2*768, 3*768, tc, td);
  ln_k<1><<<B_, blk, 0, stream>>>(tc, td, nullptr, ln_g, ln_b, 2*D_, fz0);
  // m4: q proj + fused K|V proj over gathered ans rows (128-tile pipelined) + attention
  gemm_k<0,1,0><<<gg(B_,D_), blk, 0, stream>>>(fz0, NORIDX, m_in_w, 4*IW, m_in_b, 4*2304, qh, NOS, NOS, B_, D_, D_, D_);
  gemm128_k<1,0,1><<<g128(B_*K_, 2*D_), blk, 0, stream>>>(ans, run_id, m_in_w + 4*IW + KOFF, m_in_b + 4*2304 + 768, kvh, NOS, NOS, B_*K_, 2*D_, D_, 2*D_);
  attn2_k<<<(B_*8+63)/64, dim3(64), 0, stream>>>(qh, kvh, o4);
  gemm_k<0,1,0><<<gg(B_,D_), blk, 0, stream>>>(o4, NORIDX, m_out_w, 4*OW, m_out_b, 4*768, ta, NOS, NOS, B_, D_, D_, D_);
  ln_k<1><<<B_, blk, 0, stream>>>(fz0, ta, nullptr, ln_g, ln_b, 3*D_, fz);
  // FFN: w1 via 128-tile fused gelu; w2 via split-K x4 + deterministic sum (+bias+residual)
  gemm128_k<2,0,0><<<g128(B_,4*D_), blk, 0, stream>>>(fz, NORIDX, ffn_w1, ffn_b1, h1, NOS, NOS, B_, 4*D_, D_, 4*D_);
  gemmsk_k<<<dim3(12,16,4), blk, 0, stream>>>(h1, ffn_w2, pK);
  sum4_k<<<ng(B_,D_), blk, 0, stream>>>(pK, fz, ffn_b2, ta);
  gemm_k<0,1,0><<<gg(B_,D_), blk, 0, stream>>>(ta, NORIDX, outp_w, 0, outp_b, 0, outv, NOS, NOS, B_, D_, D_, D_);
  gemm_k<0,2,0><<<gg(B_,D_), blk, 0, stream>>>(outv, NORIDX, open_w1, 0, open_b1, 0, g1, NOS, NOS, B_, D_, D_, D_);
  gemm128_k<1,0,0><<<g128(B_,N_), blk, 0, stream>>>(g1, NORIDX, open_w2, open_b2, (float*)d_out, NOS, NOS, B_, N_, D_, N_);
}